// Round 3
// baseline (62893.457 us; speedup 1.0000x reference)
//
#include <hip/hip_runtime.h>
#include <hip/hip_bf16.h>

// LSTM_27144193311539: B=64,T=1024,D=128,H=1024,C=128. fp32 in/out.
// Round 9: halve dec broadcast volume. Four single-matrix roles of 64 WGs,
// each WG owns 16 h-cols (64 gate-rows x K=1024 = 129KB LDS):
//   p1a (wg 0..63):    Wfold;  I1: f1b seg + pbuf0 partial -> cell d0(t).
//                              I3: fc1 mm4 -> f1(t).
//   p1b (wg 64..127):  Whh0d;  I2 (n<32) / I3 (n>=32): d0(t) seg -> pbuf0.
//                              wg 64..71 also run pred in I1.
//   p2a (wg 128..191): Wih1d;  I2: d0(t) seg + pbuf1 partial -> cell d1(t).
//   p2b (wg 192..255): Whh1d;  I3: d1(t) seg -> pbuf1.
// Partials are dumped/reloaded in exact register-lane order (16 f32/lane,
// coalesced dwordx4, coherent). Segments drop from 128 to 64 reader-WGs:
// 16MB -> 8MB each; dec step ~66MB -> ~38MB. Cell is now lane-local
// (4 gate accums per lane, no shfl pairing). Single d0/d1/f1b buffers
// (reads of step t complete at a gbar before the t+1 overwrite).
// Encoder unchanged (R6-proven): L1 needs both matrices, LDS forbids 16-col.

typedef __hip_bfloat16 hbf16;
typedef __bf16 bf16x8 __attribute__((ext_vector_type(8)));
typedef float f32x4 __attribute__((ext_vector_type(4)));
#define DEVI static __device__ __forceinline__

#define PITCH 2056   // enc LDS row pitch (elems) for K=2048
#define PITCH0 1160  // enc LDS row pitch for layer0 K=1152
#define PITCH1 1032  // dec LDS row pitch for K=1024 (2064B=516dw=4 mod 32)

DEVI float sigf(float x) { return 1.0f / (1.0f + __expf(-x)); }

DEVI bf16x8 as_bf(f32x4 v) { union { f32x4 f; bf16x8 b; } u; u.f = v; return u.b; }

// ---- coherent store helpers (fire-and-forget; drained at barrier)
DEVI void st_u32_coh(void* p, unsigned int v) {
  __hip_atomic_store((unsigned int*)p, v, __ATOMIC_RELAXED, __HIP_MEMORY_SCOPE_AGENT);
}
DEVI void st_u64_coh(void* p, unsigned long long v) {
  __hip_atomic_store((unsigned long long*)p, v, __ATOMIC_RELAXED, __HIP_MEMORY_SCOPE_AGENT);
}
DEVI void st_f32_coh(float* p, float v) {
  __hip_atomic_store(p, v, __ATOMIC_RELAXED, __HIP_MEMORY_SCOPE_AGENT);
}
DEVI void st16_coh(float* p, f32x4 v) {
  asm volatile("global_store_dwordx4 %0, %1, off sc0 sc1"
               :: "v"(p), "v"(v) : "memory");
}
DEVI unsigned short bf_bits(float v) {
  union { __hip_bfloat16 b; unsigned short s; } u;
  u.b = __float2bfloat16(v);
  return u.s;
}

// ---- ONE asm block: 32 coherent 16B loads from ap (+64B steps) + wait.
DEVI void ld32_wait(f32x4* b, const hbf16* ap) {
  asm volatile(
    "global_load_dwordx4 %0, %32, off sc0 sc1\n\t"
    "global_load_dwordx4 %1, %32, off offset:64 sc0 sc1\n\t"
    "global_load_dwordx4 %2, %32, off offset:128 sc0 sc1\n\t"
    "global_load_dwordx4 %3, %32, off offset:192 sc0 sc1\n\t"
    "global_load_dwordx4 %4, %32, off offset:256 sc0 sc1\n\t"
    "global_load_dwordx4 %5, %32, off offset:320 sc0 sc1\n\t"
    "global_load_dwordx4 %6, %32, off offset:384 sc0 sc1\n\t"
    "global_load_dwordx4 %7, %32, off offset:448 sc0 sc1\n\t"
    "global_load_dwordx4 %8, %32, off offset:512 sc0 sc1\n\t"
    "global_load_dwordx4 %9, %32, off offset:576 sc0 sc1\n\t"
    "global_load_dwordx4 %10, %32, off offset:640 sc0 sc1\n\t"
    "global_load_dwordx4 %11, %32, off offset:704 sc0 sc1\n\t"
    "global_load_dwordx4 %12, %32, off offset:768 sc0 sc1\n\t"
    "global_load_dwordx4 %13, %32, off offset:832 sc0 sc1\n\t"
    "global_load_dwordx4 %14, %32, off offset:896 sc0 sc1\n\t"
    "global_load_dwordx4 %15, %32, off offset:960 sc0 sc1\n\t"
    "global_load_dwordx4 %16, %32, off offset:1024 sc0 sc1\n\t"
    "global_load_dwordx4 %17, %32, off offset:1088 sc0 sc1\n\t"
    "global_load_dwordx4 %18, %32, off offset:1152 sc0 sc1\n\t"
    "global_load_dwordx4 %19, %32, off offset:1216 sc0 sc1\n\t"
    "global_load_dwordx4 %20, %32, off offset:1280 sc0 sc1\n\t"
    "global_load_dwordx4 %21, %32, off offset:1344 sc0 sc1\n\t"
    "global_load_dwordx4 %22, %32, off offset:1408 sc0 sc1\n\t"
    "global_load_dwordx4 %23, %32, off offset:1472 sc0 sc1\n\t"
    "global_load_dwordx4 %24, %32, off offset:1536 sc0 sc1\n\t"
    "global_load_dwordx4 %25, %32, off offset:1600 sc0 sc1\n\t"
    "global_load_dwordx4 %26, %32, off offset:1664 sc0 sc1\n\t"
    "global_load_dwordx4 %27, %32, off offset:1728 sc0 sc1\n\t"
    "global_load_dwordx4 %28, %32, off offset:1792 sc0 sc1\n\t"
    "global_load_dwordx4 %29, %32, off offset:1856 sc0 sc1\n\t"
    "global_load_dwordx4 %30, %32, off offset:1920 sc0 sc1\n\t"
    "global_load_dwordx4 %31, %32, off offset:1984 sc0 sc1\n\t"
    "s_waitcnt vmcnt(0)"
    : "=&v"(b[0]), "=&v"(b[1]), "=&v"(b[2]), "=&v"(b[3]),
      "=&v"(b[4]), "=&v"(b[5]), "=&v"(b[6]), "=&v"(b[7]),
      "=&v"(b[8]), "=&v"(b[9]), "=&v"(b[10]), "=&v"(b[11]),
      "=&v"(b[12]), "=&v"(b[13]), "=&v"(b[14]), "=&v"(b[15]),
      "=&v"(b[16]), "=&v"(b[17]), "=&v"(b[18]), "=&v"(b[19]),
      "=&v"(b[20]), "=&v"(b[21]), "=&v"(b[22]), "=&v"(b[23]),
      "=&v"(b[24]), "=&v"(b[25]), "=&v"(b[26]), "=&v"(b[27]),
      "=&v"(b[28]), "=&v"(b[29]), "=&v"(b[30]), "=&v"(b[31])
    : "v"(ap) : "memory");
}

// ---- ONE asm block: 4 row-tiles x 8 coherent 16B loads + wait (fc1/pred).
DEVI void ld4x8_wait(f32x4* b, const hbf16* a0, const hbf16* a1,
                     const hbf16* a2, const hbf16* a3) {
  asm volatile(
    "global_load_dwordx4 %0, %32, off sc0 sc1\n\t"
    "global_load_dwordx4 %1, %32, off offset:64 sc0 sc1\n\t"
    "global_load_dwordx4 %2, %32, off offset:128 sc0 sc1\n\t"
    "global_load_dwordx4 %3, %32, off offset:192 sc0 sc1\n\t"
    "global_load_dwordx4 %4, %32, off offset:256 sc0 sc1\n\t"
    "global_load_dwordx4 %5, %32, off offset:320 sc0 sc1\n\t"
    "global_load_dwordx4 %6, %32, off offset:384 sc0 sc1\n\t"
    "global_load_dwordx4 %7, %32, off offset:448 sc0 sc1\n\t"
    "global_load_dwordx4 %8, %33, off sc0 sc1\n\t"
    "global_load_dwordx4 %9, %33, off offset:64 sc0 sc1\n\t"
    "global_load_dwordx4 %10, %33, off offset:128 sc0 sc1\n\t"
    "global_load_dwordx4 %11, %33, off offset:192 sc0 sc1\n\t"
    "global_load_dwordx4 %12, %33, off offset:256 sc0 sc1\n\t"
    "global_load_dwordx4 %13, %33, off offset:320 sc0 sc1\n\t"
    "global_load_dwordx4 %14, %33, off offset:384 sc0 sc1\n\t"
    "global_load_dwordx4 %15, %33, off offset:448 sc0 sc1\n\t"
    "global_load_dwordx4 %16, %34, off sc0 sc1\n\t"
    "global_load_dwordx4 %17, %34, off offset:64 sc0 sc1\n\t"
    "global_load_dwordx4 %18, %34, off offset:128 sc0 sc1\n\t"
    "global_load_dwordx4 %19, %34, off offset:192 sc0 sc1\n\t"
    "global_load_dwordx4 %20, %34, off offset:256 sc0 sc1\n\t"
    "global_load_dwordx4 %21, %34, off offset:320 sc0 sc1\n\t"
    "global_load_dwordx4 %22, %34, off offset:384 sc0 sc1\n\t"
    "global_load_dwordx4 %23, %34, off offset:448 sc0 sc1\n\t"
    "global_load_dwordx4 %24, %35, off sc0 sc1\n\t"
    "global_load_dwordx4 %25, %35, off offset:64 sc0 sc1\n\t"
    "global_load_dwordx4 %26, %35, off offset:128 sc0 sc1\n\t"
    "global_load_dwordx4 %27, %35, off offset:192 sc0 sc1\n\t"
    "global_load_dwordx4 %28, %35, off offset:256 sc0 sc1\n\t"
    "global_load_dwordx4 %29, %35, off offset:320 sc0 sc1\n\t"
    "global_load_dwordx4 %30, %35, off offset:384 sc0 sc1\n\t"
    "global_load_dwordx4 %31, %35, off offset:448 sc0 sc1\n\t"
    "s_waitcnt vmcnt(0)"
    : "=&v"(b[0]), "=&v"(b[1]), "=&v"(b[2]), "=&v"(b[3]),
      "=&v"(b[4]), "=&v"(b[5]), "=&v"(b[6]), "=&v"(b[7]),
      "=&v"(b[8]), "=&v"(b[9]), "=&v"(b[10]), "=&v"(b[11]),
      "=&v"(b[12]), "=&v"(b[13]), "=&v"(b[14]), "=&v"(b[15]),
      "=&v"(b[16]), "=&v"(b[17]), "=&v"(b[18]), "=&v"(b[19]),
      "=&v"(b[20]), "=&v"(b[21]), "=&v"(b[22]), "=&v"(b[23]),
      "=&v"(b[24]), "=&v"(b[25]), "=&v"(b[26]), "=&v"(b[27]),
      "=&v"(b[28]), "=&v"(b[29]), "=&v"(b[30]), "=&v"(b[31])
    : "v"(a0), "v"(a1), "v"(a2), "v"(a3) : "memory");
}

// ---- 4 coherent 16B loads (partial reload) + wait.
DEVI void ld4_wait(f32x4* b, const float* ap) {
  asm volatile(
    "global_load_dwordx4 %0, %4, off sc0 sc1\n\t"
    "global_load_dwordx4 %1, %4, off offset:16 sc0 sc1\n\t"
    "global_load_dwordx4 %2, %4, off offset:32 sc0 sc1\n\t"
    "global_load_dwordx4 %3, %4, off offset:48 sc0 sc1\n\t"
    "s_waitcnt vmcnt(0)"
    : "=&v"(b[0]), "=&v"(b[1]), "=&v"(b[2]), "=&v"(b[3])
    : "v"(ap) : "memory");
}

// ---- grid barrier: vmcnt drain (coherent stores at MALL) + flag array.
DEVI void gbar(int* flags, int e) {
  asm volatile("s_waitcnt vmcnt(0) lgkmcnt(0)" ::: "memory");
  __syncthreads();
  if (threadIdx.x == 0)
    __hip_atomic_store(&flags[blockIdx.x], e, __ATOMIC_RELAXED, __HIP_MEMORY_SCOPE_AGENT);
  while (__hip_atomic_load(&flags[threadIdx.x], __ATOMIC_RELAXED,
                           __HIP_MEMORY_SCOPE_AGENT) < e)
    __builtin_amdgcn_s_sleep(1);
  __syncthreads();
}

// ---- cooperative LDS weight fill, enc variant (32 rows, 8 h-cols)
DEVI void fill_w(hbf16* W, int pitch, int koff, const hbf16* __restrict__ Wg,
                 int Kg, int base_h) {
  for (int r = (int)(threadIdx.x >> 3); r < 32; r += 32) {
    int g = r >> 3, hc = r & 7;
    const hbf16* src = Wg + (long)(g * 1024 + base_h + hc) * Kg;
    hbf16* dst = W + r * pitch + koff;
    for (int k = (threadIdx.x & 7) * 8; k < Kg; k += 64)
      *reinterpret_cast<bf16x8*>(dst + k) =
          *reinterpret_cast<const bf16x8*>(src + k);
  }
}

// ---- dec LDS weight fill: 64 rows (16 h-cols x 4 gates), K=1024
DEVI void fill_w16(hbf16* W, const hbf16* __restrict__ Wg, int base16) {
  int r = (int)(threadIdx.x >> 2);   // 64 rows, 4 threads/row
  int g = r >> 4, hc = r & 15;
  const hbf16* src = Wg + (long)(g * 1024 + base16 + hc) * 1024;
  hbf16* dst = W + r * PITCH1;
  for (int k = (threadIdx.x & 3) * 8; k < 1024; k += 32)
    *reinterpret_cast<bf16x8*>(dst + k) =
        *reinterpret_cast<const bf16x8*>(src + k);
}

// ---- enc coherent K=1024 gate-GEMM segment (2 accums, 8 h-cols)
DEVI void seg_asm(f32x4& a0, f32x4& a1, const hbf16* __restrict__ A, long lda,
                  const hbf16* W, int pitch, int koff, int w, int q, int r16) {
  const hbf16* ap = A + (long)(w * 16 + r16) * lda + q * 8;
  const hbf16* w0 = W + r16 * pitch + koff + q * 8;
  const hbf16* w1 = W + (16 + r16) * pitch + koff + q * 8;
  f32x4 b[32];
  ld32_wait(b, ap);
#pragma unroll
  for (int k = 0; k < 32; ++k) {
    bf16x8 av = as_bf(b[k]);
    bf16x8 b0 = *reinterpret_cast<const bf16x8*>(w0 + k * 32);
    bf16x8 b1 = *reinterpret_cast<const bf16x8*>(w1 + k * 32);
    a0 = __builtin_amdgcn_mfma_f32_16x16x32_bf16(av, b0, a0, 0, 0, 0);
    a1 = __builtin_amdgcn_mfma_f32_16x16x32_bf16(av, b1, a1, 0, 0, 0);
  }
}

// ---- dec coherent K=1024 segment: 4 gate accums, 16 h-cols per WG.
DEVI void seg16(f32x4* a, const hbf16* __restrict__ A, const hbf16* W,
                int w, int q, int c) {
  const hbf16* ap = A + (long)(w * 16 + c) * 1024 + q * 8;
  const hbf16* w0 = W + c * PITCH1 + q * 8;
  const hbf16* w1 = W + (16 + c) * PITCH1 + q * 8;
  const hbf16* w2 = W + (32 + c) * PITCH1 + q * 8;
  const hbf16* w3 = W + (48 + c) * PITCH1 + q * 8;
  f32x4 b[32];
  ld32_wait(b, ap);
#pragma unroll
  for (int k = 0; k < 32; ++k) {
    bf16x8 av = as_bf(b[k]);
    a[0] = __builtin_amdgcn_mfma_f32_16x16x32_bf16(
        av, *reinterpret_cast<const bf16x8*>(w0 + k * 32), a[0], 0, 0, 0);
    a[1] = __builtin_amdgcn_mfma_f32_16x16x32_bf16(
        av, *reinterpret_cast<const bf16x8*>(w1 + k * 32), a[1], 0, 0, 0);
    a[2] = __builtin_amdgcn_mfma_f32_16x16x32_bf16(
        av, *reinterpret_cast<const bf16x8*>(w2 + k * 32), a[2], 0, 0, 0);
    a[3] = __builtin_amdgcn_mfma_f32_16x16x32_bf16(
        av, *reinterpret_cast<const bf16x8*>(w3 + k * 32), a[3], 0, 0, 0);
  }
}

// ---- plain K=128 segment (enc L0 x-input; read-only, normal caching)
DEVI void seg_x(f32x4& a0, f32x4& a1, const hbf16* __restrict__ A, long lda,
                const hbf16* W, int pitch, int w, int q, int r16) {
  const hbf16* ap = A + (long)(w * 16 + r16) * lda + q * 8;
  const hbf16* w0 = W + r16 * pitch + q * 8;
  const hbf16* w1 = W + (16 + r16) * pitch + q * 8;
#pragma unroll
  for (int k = 0; k < 128; k += 32) {
    bf16x8 av = *reinterpret_cast<const bf16x8*>(ap + k);
    bf16x8 b0 = *reinterpret_cast<const bf16x8*>(w0 + k);
    bf16x8 b1 = *reinterpret_cast<const bf16x8*>(w1 + k);
    a0 = __builtin_amdgcn_mfma_f32_16x16x32_bf16(av, b0, a0, 0, 0, 0);
    a1 = __builtin_amdgcn_mfma_f32_16x16x32_bf16(av, b1, a1, 0, 0, 0);
  }
}

// ---- 4-m-tile x K=256 slice GEMM (fc1 / pred): one batched round-trip.
DEVI void mm4_asm(f32x4* pa, const hbf16* __restrict__ abase, const bf16x8* fr) {
  f32x4 b[32];
  ld4x8_wait(b, abase, abase + 16384, abase + 32768, abase + 49152);
#pragma unroll
  for (int i = 0; i < 8; ++i)
#pragma unroll
    for (int mt = 0; mt < 4; ++mt)
      pa[mt] = __builtin_amdgcn_mfma_f32_16x16x32_bf16(
          as_bf(b[mt * 8 + i]), fr[i], pa[mt], 0, 0, 0);
}

// ---- enc LSTM cell (8-col packing, shfl-paired gates)
DEVI void cell(f32x4 a0, f32x4 a1, float bb0, float bb1, float* cst,
               hbf16* __restrict__ hout, int base_h, int lane, int w) {
  int q = lane >> 4, c = lane & 15;
#pragma unroll
  for (int r = 0; r < 4; ++r) {
    float z0 = a0[r] + bb0;
    float z1 = a1[r] + bb1;
    float zf = __shfl(z0, lane | 8, 64);
    float zo = __shfl(z1, lane | 8, 64);
    float hv = 0.f;
    if (c < 8) {
      float cn = sigf(zf) * cst[r] + sigf(z0) * tanhf(z1);
      cst[r] = cn;
      hv = sigf(zo) * tanhf(cn);
    }
    unsigned short my = bf_bits(hv);
    unsigned short nb = (unsigned short)__shfl((int)my, lane ^ 1, 64);
    if (c < 8 && (c & 1) == 0) {
      unsigned int pk = (unsigned int)my | ((unsigned int)nb << 16);
      st_u32_coh(hout + (long)(w * 16 + q * 4 + r) * 1024 + base_h + c, pk);
    }
  }
}

// ---- dec LSTM cell: 4 gate accums per lane, fully lane-local.
DEVI void cell16(const f32x4* a, const float* bb, float* cst,
                 hbf16* __restrict__ hout, int base16, int lane, int w) {
  int q = lane >> 4, c = lane & 15;
#pragma unroll
  for (int r = 0; r < 4; ++r) {
    float zi = a[0][r] + bb[0];
    float zf = a[1][r] + bb[1];
    float zg = a[2][r] + bb[2];
    float zo = a[3][r] + bb[3];
    float cn = sigf(zf) * cst[r] + sigf(zi) * tanhf(zg);
    cst[r] = cn;
    float hv = sigf(zo) * tanhf(cn);
    unsigned short my = bf_bits(hv);
    unsigned short nb = (unsigned short)__shfl((int)my, lane ^ 1, 64);
    if ((c & 1) == 0) {
      unsigned int pk = (unsigned int)my | ((unsigned int)nb << 16);
      st_u32_coh(hout + (long)(w * 16 + q * 4 + r) * 1024 + base16 + c, pk);
    }
  }
}

DEVI void dump_partial(const f32x4* a, float* pb, int tid) {
  float* p = pb + tid * 16;
#pragma unroll
  for (int g = 0; g < 4; ++g) st16_coh(p + g * 4, a[g]);
}

DEVI void add_partial(f32x4* a, const float* pb, int tid) {
  f32x4 b[4];
  ld4_wait(b, pb + tid * 16);
#pragma unroll
  for (int g = 0; g < 4; ++g) a[g] += b[g];
}

DEVI void store_c(const float* cst, float* cbuf, int hcol_g, int lane, int w) {
  int q = lane >> 4, c = lane & 15;
  if (c < 8) {
#pragma unroll
    for (int r = 0; r < 4; ++r)
      st_f32_coh(&cbuf[(long)(w * 16 + q * 4 + r) * 1024 + hcol_g], cst[r]);
  }
}

// ================= encoder persistent kernel (R6 verbatim) =================
__global__ __launch_bounds__(256, 1) void k_enc(
    const hbf16* __restrict__ xb,
    const hbf16* __restrict__ Wih0f, const hbf16* __restrict__ Whh0,
    const hbf16* __restrict__ Wih1, const hbf16* __restrict__ Whh1,
    const float* __restrict__ b0f, const float* __restrict__ b1f,
    hbf16* h0_0, hbf16* h0_1, hbf16* h1_0, hbf16* h1_1,
    float* c0buf, float* c1buf, int* flags) {
  __shared__ hbf16 W[32 * PITCH];
  int wg = blockIdx.x, tid = threadIdx.x;
  int lane = tid & 63, w = tid >> 6, q = lane >> 4, c = lane & 15;
  bool isL0 = wg < 128;
  int cu = isL0 ? wg : wg - 128;
  int base_h = cu * 8;
  if (isL0) {
    fill_w(W, PITCH0, 0, Wih0f, 128, base_h);
    fill_w(W, PITCH0, 128, Whh0, 1024, base_h);
  } else {
    fill_w(W, PITCH, 0, Wih1, 1024, base_h);
    fill_w(W, PITCH, 1024, Whh1, 1024, base_h);
  }
  __syncthreads();
  const float* bias = isL0 ? b0f : b1f;
  float bb0 = bias[(c >> 3) * 1024 + base_h + (c & 7)];
  float bb1 = bias[(2 + (c >> 3)) * 1024 + base_h + (c & 7)];
  float cst[4] = {0.f, 0.f, 0.f, 0.f};
  int hcol_g = base_h + (c & 7);

  for (int t = 0; t <= 1024; ++t) {
    if (isL0) {
      if (t < 1024) {
        f32x4 a0 = {0.f,0.f,0.f,0.f}, a1 = {0.f,0.f,0.f,0.f};
        const hbf16* h0r = (t & 1) ? h0_0 : h0_1;   // h0(t-1)
        seg_asm(a0, a1, h0r, 1024L, W, PITCH0, 128, w, q, c);  // coherent first
        seg_x(a0, a1, xb + (long)t * 128, 131072L, W, PITCH0, w, q, c);
        hbf16* h0w = (t & 1) ? h0_1 : h0_0;         // h0(t)
        cell(a0, a1, bb0, bb1, cst, h0w, base_h, lane, w);
        if (t == 1023) store_c(cst, c0buf, hcol_g, lane, w);
      }
    } else {
      if (t >= 1) {   // computes h1(t-1)
        f32x4 a0 = {0.f,0.f,0.f,0.f}, a1 = {0.f,0.f,0.f,0.f};
        const hbf16* h0r = (t & 1) ? h0_0 : h0_1;   // h0(t-1)
        seg_asm(a0, a1, h0r, 1024L, W, PITCH, 0, w, q, c);
        const hbf16* h1r = (t & 1) ? h1_1 : h1_0;   // h1(t-2)
        seg_asm(a0, a1, h1r, 1024L, W, PITCH, 1024, w, q, c);
        hbf16* h1w = (t & 1) ? h1_0 : h1_1;         // h1(t-1)
        cell(a0, a1, bb0, bb1, cst, h1w, base_h, lane, w);
        if (t == 1024) store_c(cst, c1buf, hcol_g, lane, w);
      }
    }
    if (t < 1024) gbar(flags, t + 1);
  }
}

// ================= decoder persistent kernel =================
__global__ __launch_bounds__(256, 1) void k_dec(
    const hbf16* __restrict__ Wfold, const hbf16* __restrict__ Whh0d,
    const hbf16* __restrict__ Wih1d, const hbf16* __restrict__ Whh1d,
    const float* __restrict__ b0t, const float* __restrict__ b0p,
    const float* __restrict__ b1d,
    const hbf16* __restrict__ fc1Wf, const float* __restrict__ fc1bf,
    const float* __restrict__ fs2, const float* __restrict__ fadd2,
    const hbf16* __restrict__ fc2Wb, const float* __restrict__ fc2b,
    hbf16* d0, hbf16* d1, hbf16* f1b,
    const float* __restrict__ c0buf, const float* __restrict__ c1buf,
    float* pbuf0, float* pbuf1,
    float* __restrict__ out, int* flags) {
  __shared__ hbf16 W[64 * PITCH1];
  __shared__ float bounce[4][64][16];
  int wg = blockIdx.x, tid = threadIdx.x;
  int lane = tid & 63, w = tid >> 6, q = lane >> 4, c = lane & 15;
  int role = wg >> 6;          // 0=p1a(Wfold), 1=p1b(Whh0d), 2=p2a(Wih1d), 3=p2b(Whh1d)
  int n = wg & 63;
  int base16 = n * 16;
  {
    const hbf16* Wsrc = (role == 0) ? Wfold : (role == 1) ? Whh0d
                       : (role == 2) ? Wih1d : Whh1d;
    fill_w16(W, Wsrc, base16);
  }
  __syncthreads();
  // biases
  float bt[4] = {0,0,0,0}, bp[4] = {0,0,0,0};
  if (role == 0) {
#pragma unroll
    for (int g = 0; g < 4; ++g) {
      bt[g] = b0t[g * 1024 + base16 + c];
      bp[g] = b0p[g * 1024 + base16 + c];
    }
  } else if (role == 2) {
#pragma unroll
    for (int g = 0; g < 4; ++g) bt[g] = b1d[g * 1024 + base16 + c];
  }
  // cell-state handoff from encoder (plain cached loads, cross-kernel OK)
  float cst[4] = {0.f, 0.f, 0.f, 0.f};
  if (role == 0 || role == 2) {
    const float* cb = (role == 0) ? c0buf : c1buf;
#pragma unroll
    for (int r = 0; r < 4; ++r)
      cst[r] = cb[(long)(w * 16 + q * 4 + r) * 1024 + base16 + c];
  }
  // aux roles: fc1 on p1a (all 64); pred on first 8 of p1b
  bool isPred = (wg >= 64 && wg < 72);
  bf16x8 fr[8];
#pragma unroll
  for (int i = 0; i < 8; ++i) fr[i] = bf16x8{0,0,0,0,0,0,0,0};
  float e_b[4] = {0,0,0,0}, e_s[4] = {0,0,0,0}, e_a[4] = {0,0,0,0};
  int red_row = tid >> 2, red_c4 = (tid & 3) * 4;
  if (role == 0) {   // fc1 weights: 16 output cols n*16.., K-slice w*256
    const hbf16* fp = fc1Wf + (long)(n * 16 + c) * 1024 + w * 256 + q * 8;
#pragma unroll
    for (int i = 0; i < 8; ++i) fr[i] = *reinterpret_cast<const bf16x8*>(fp + i * 32);
#pragma unroll
    for (int i = 0; i < 4; ++i) {
      int col = n * 16 + red_c4 + i;
      e_b[i] = fc1bf[col]; e_s[i] = fs2[col]; e_a[i] = fadd2[col];
    }
  } else if (isPred) {
    const hbf16* fp = fc2Wb + (long)((wg - 64) * 16 + c) * 1024 + w * 256 + q * 8;
#pragma unroll
    for (int i = 0; i < 8; ++i) fr[i] = *reinterpret_cast<const bf16x8*>(fp + i * 32);
#pragma unroll
    for (int i = 0; i < 4; ++i) e_b[i] = fc2b[(wg - 64) * 16 + red_c4 + i];
  }

  // ---- pre-loop: partials from encoder finals (d0 = enc h0, d1 = enc h1)
  if (role == 1) {
    f32x4 a[4] = {{0,0,0,0},{0,0,0,0},{0,0,0,0},{0,0,0,0}};
    seg16(a, d0, W, w, q, c);
    dump_partial(a, pbuf0 + n * 4096, tid);
  } else if (role == 3) {
    f32x4 a[4] = {{0,0,0,0},{0,0,0,0},{0,0,0,0},{0,0,0,0}};
    seg16(a, d1, W, w, q, c);
    dump_partial(a, pbuf1 + n * 4096, tid);
  }
  gbar(flags, 1);

  for (int t = 0; t <= 1024; ++t) {
    // ---- interval 1: p1a gates d0(t); pred(t-1) on pred-WGs
    if (role == 0 && t < 1024) {
      f32x4 a[4] = {{0,0,0,0},{0,0,0,0},{0,0,0,0},{0,0,0,0}};
      if (t > 0) seg16(a, f1b, W, w, q, c);
      add_partial(a, pbuf0 + n * 4096, tid);
      cell16(a, (t > 0) ? bt : bp, cst, d0, base16, lane, w);
    }
    if (isPred && t >= 1) {   // pred(t-1) = f1(t-1)@fc2^T + fc2_b -> out
      f32x4 pa[4] = {{0,0,0,0},{0,0,0,0},{0,0,0,0},{0,0,0,0}};
      mm4_asm(pa, f1b + (long)c * 1024 + w * 256 + q * 8, fr);
#pragma unroll
      for (int mt = 0; mt < 4; ++mt)
#pragma unroll
        for (int r = 0; r < 4; ++r) bounce[w][mt * 16 + q * 4 + r][c] = pa[mt][r];
      __syncthreads();
#pragma unroll
      for (int i = 0; i < 4; ++i) {
        int cc = red_c4 + i;
        float s = bounce[0][red_row][cc] + bounce[1][red_row][cc] +
                  bounce[2][red_row][cc] + bounce[3][red_row][cc] + e_b[i];
        out[(long)red_row * 131072 + (long)(t - 1) * 128 + (wg - 64) * 16 + cc] = s;
      }
    }
    if (t == 1024) break;
    gbar(flags, 3 * t + 2);
    // ---- interval 2: p2a gates d1(t); p1b first half -> pbuf0 for t+1
    if (role == 2) {
      f32x4 a[4] = {{0,0,0,0},{0,0,0,0},{0,0,0,0},{0,0,0,0}};
      seg16(a, d0, W, w, q, c);
      add_partial(a, pbuf1 + n * 4096, tid);
      cell16(a, bt, cst, d1, base16, lane, w);
    } else if (role == 1 && n < 32 && t < 1023) {
      f32x4 a[4] = {{0,0,0,0},{0,0,0,0},{0,0,0,0},{0,0,0,0}};
      seg16(a, d0, W, w, q, c);
      dump_partial(a, pbuf0 + n * 4096, tid);
    }
    gbar(flags, 3 * t + 3);
    // ---- interval 3: p1a: fc1 -> f1(t); p1b second half -> pbuf0;
    //                  p2b -> pbuf1 for t+1
    if (role == 0) {
      f32x4 pa[4] = {{0,0,0,0},{0,0,0,0},{0,0,0,0},{0,0,0,0}};
      mm4_asm(pa, d1 + (long)c * 1024 + w * 256 + q * 8, fr);
#pragma unroll
      for (int mt = 0; mt < 4; ++mt)
#pragma unroll
        for (int r = 0; r < 4; ++r) bounce[w][mt * 16 + q * 4 + r][c] = pa[mt][r];
      __syncthreads();
#pragma unroll
      for (int i = 0; i < 4; ++i) {
        int cc = red_c4 + i;
        float s = bounce[0][red_row][cc] + bounce[1][red_row][cc] +
                  bounce[2][red_row][cc] + bounce[3][red_row][cc];
        float v = fmaxf((s + e_b[i]) * e_s[i] + e_a[i], 0.f);
        bounce[0][red_row][cc] = v;   // stage for packed store
      }
      {
        union { unsigned short s4[4]; unsigned long long u; } pk;
#pragma unroll
        for (int i = 0; i < 4; ++i) pk.s4[i] = bf_bits(bounce[0][red_row][red_c4 + i]);
        st_u64_coh(f1b + (long)red_row * 1024 + n * 16 + red_c4, pk.u);
      }
    } else if (role == 1 && n >= 32 && t < 1023) {
      f32x4 a[4] = {{0,0,0,0},{0,0,0,0},{0,0,0,0},{0,0,0,0}};
      seg16(a, d0, W, w, q, c);
      dump_partial(a, pbuf0 + n * 4096, tid);
    } else if (role == 3 && t < 1023) {
      f32x4 a[4] = {{0,0,0,0},{0,0,0,0},{0,0,0,0},{0,0,0,0}};
      seg16(a, d1, W, w, q, c);
      dump_partial(a, pbuf1 + n * 4096, tid);
    }
    gbar(flags, 3 * t + 4);
  }
}

// ================= prep kernels (verified in R2) =================

__global__ void k_cast_bf16(const float* __restrict__ s, hbf16* __restrict__ d, long n) {
  long i = (long)blockIdx.x * blockDim.x + threadIdx.x;
  long stride = (long)gridDim.x * blockDim.x;
  for (; i < n; i += stride) d[i] = __float2bfloat16(s[i]);
}

__global__ void k_prep_b0tot(const float* __restrict__ dec_b0, const float* __restrict__ dWih0,
                             const float* __restrict__ fc2b, float* __restrict__ b0d_tot) {
  int n = blockIdx.x * 256 + threadIdx.x;
  float acc = 0.f;
  for (int cc = 0; cc < 128; ++cc) acc += dWih0[n * 128 + cc] * fc2b[cc];
  b0d_tot[n] = dec_b0[n] + acc;
}

__global__ void k_fold_ih0(const float* __restrict__ g, const float* __restrict__ bb,
                           const float* __restrict__ m, const float* __restrict__ v,
                           const float* __restrict__ Wm, const float* __restrict__ b0,
                           hbf16* __restrict__ Wf, float* __restrict__ biasf) {
  int n = blockIdx.x * 256 + threadIdx.x;
  float acc = 0.f;
  for (int k = 0; k < 128; ++k) {
    float s = g[k] * rsqrtf(v[k] + 1e-5f);
    float tt = bb[k] - m[k] * s;
    float wv = Wm[n * 128 + k];
    Wf[n * 128 + k] = __float2bfloat16(wv * s);
    acc += tt * wv;
  }
  biasf[n] = b0[n] + acc;
}

__global__ void k_fold_fc1(const float* __restrict__ hg, const float* __restrict__ hb,
                           const float* __restrict__ hm, const float* __restrict__ hv,
                           const float* __restrict__ Wm, const float* __restrict__ fb,
                           const float* __restrict__ fg, const float* __restrict__ fbb,
                           const float* __restrict__ fm, const float* __restrict__ fv,
                           hbf16* __restrict__ Wf, float* __restrict__ bfo,
                           float* __restrict__ fs2, float* __restrict__ fadd2) {
  int n = blockIdx.x * 256 + threadIdx.x;
  float acc = 0.f;
  for (int k = 0; k < 1024; ++k) {
    float s = hg[k] * rsqrtf(hv[k] + 1e-5f);
    float tt = hb[k] - hm[k] * s;
    float wv = Wm[(long)n * 1024 + k];
    Wf[(long)n * 1024 + k] = __float2bfloat16(wv * s);
    acc += tt * wv;
  }
  bfo[n] = fb[n] + acc;
  float s2 = fg[n] * rsqrtf(fv[n] + 1e-5f);
  fs2[n] = s2;
  fadd2[n] = fbb[n] - fm[n] * s2;
}

__global__ void k_fold_wf(const float* __restrict__ Wih0d, const float* __restrict__ fc2W,
                          hbf16* __restrict__ Wfold) {
  long gid = (long)blockIdx.x * 256 + threadIdx.x;
  int n = (int)(gid >> 10), jcol = (int)(gid & 1023);
  float acc = 0.f;
  for (int cc = 0; cc < 128; ++cc)
    acc += Wih0d[n * 128 + cc] * fc2W[cc * 1024 + jcol];
  Wfold[gid] = __float2bfloat16(acc);
}

// ================= host =================

extern "C" void kernel_launch(void* const* d_in, const int* in_sizes, int n_in,
                              void* d_out, int out_size, void* d_ws, size_t ws_size,
                              hipStream_t stream) {
  (void)in_sizes; (void)n_in; (void)out_size; (void)ws_size;
  const float* x     = (const float*)d_in[0];
  const float* ibn_g = (const float*)d_in[1];
  const float* ibn_b = (const float*)d_in[2];
  const float* ibn_m = (const float*)d_in[3];
  const float* ibn_v = (const float*)d_in[4];
  const float* eWih0 = (const float*)d_in[5];
  const float* eWhh0 = (const float*)d_in[6];
  const float* e_b0  = (const float*)d_in[7];
  const float* eWih1 = (const float*)d_in[8];
  const float* eWhh1 = (const float*)d_in[9];
  const float* e_b1  = (const float*)d_in[10];
  const float* dWih0 = (const float*)d_in[11];
  const float* dWhh0 = (const float*)d_in[12];
  const float* d_b0  = (const float*)d_in[13];
  const float* dWih1 = (const float*)d_in[14];
  const float* dWhh1 = (const float*)d_in[15];
  const float* d_b1  = (const float*)d_in[16];
  const float* hbn_g = (const float*)d_in[17];
  const float* hbn_b = (const float*)d_in[18];
  const float* hbn_m = (const float*)d_in[19];
  const float* hbn_v = (const float*)d_in[20];
  const float* fc1_W = (const float*)d_in[21];
  const float* fc1_b = (const float*)d_in[22];
  const float* fbn_g = (const float*)d_in[23];
  const float* fbn_b = (const float*)d_in[24];
  const float* fbn_m = (const float*)d_in[25];
  const float* fbn_v = (const float*)d_in[26];
  const float* fc2_W = (const float*)d_in[27];
  const float* fc2_b = (const float*)d_in[28];
  float* out = (float*)d_out;

  char* p = (char*)d_ws;
  auto alloc = [&](size_t bytes) -> void* {
    void* r = (void*)p;
    p += (bytes + 255) & ~(size_t)255;
    return r;
  };
  hbf16* xb     = (hbf16*)alloc(64L * 1024 * 128 * 2);
  hbf16* Wih0f  = (hbf16*)alloc(4096L * 128 * 2);
  hbf16* Whh0e  = (hbf16*)alloc(4096L * 1024 * 2);
  hbf16* Wih1e  = (hbf16*)alloc(4096L * 1024 * 2);
  hbf16* Whh1e  = (hbf16*)alloc(4096L * 1024 * 2);
  hbf16* Wfold  = (hbf16*)alloc(4096L * 1024 * 2);
  hbf16* Whh0d  = (hbf16*)alloc(4096L * 1024 * 2);
  hbf16* Wih1d  = (hbf16*)alloc(4096L * 1024 * 2);
  hbf16* Whh1d  = (hbf16*)alloc(4096L * 1024 * 2);
  hbf16* fc1Wf  = (hbf16*)alloc(1024L * 1024 * 2);
  hbf16* fc2Wb  = (hbf16*)alloc(128L * 1024 * 2);
  float* bias0f = (float*)alloc(4096 * 4);
  float* b0dtot = (float*)alloc(4096 * 4);
  float* fc1bf  = (float*)alloc(1024 * 4);
  float* fs2    = (float*)alloc(1024 * 4);
  float* fadd2  = (float*)alloc(1024 * 4);
  float* pbuf0  = (float*)alloc(64L * 4096 * 4);
  float* pbuf1  = (float*)alloc(64L * 4096 * 4);
  char* st = p;  // zero-init region
  hbf16* h0_0 = (hbf16*)alloc(64L * 1024 * 2);
  hbf16* h0_1 = (hbf16*)alloc(64L * 1024 * 2);
  hbf16* h1_0 = (hbf16*)alloc(64L * 1024 * 2);
  hbf16* h1_1 = (hbf16*)alloc(64L * 1024 * 2);
  float* c0b  = (float*)alloc(64L * 1024 * 4);
  float* c1b  = (float*)alloc(64L * 1024 * 4);
  hbf16* f1b  = (hbf16*)alloc(64L * 1024 * 2);
  int*   flagsE = (int*)alloc(256 * 4);
  int*   flagsD = (int*)alloc(256 * 4);
  size_t stbytes = (size_t)(p - st);

  hipMemsetAsync(st, 0, stbytes, stream);

  k_cast_bf16<<<4096, 256, 0, stream>>>(x, xb, 64L * 1024 * 128);
  k_cast_bf16<<<2048, 256, 0, stream>>>(eWhh0, Whh0e, 4096L * 1024);
  k_cast_bf16<<<2048, 256, 0, stream>>>(eWih1, Wih1e, 4096L * 1024);
  k_cast_bf16<<<2048, 256, 0, stream>>>(eWhh1, Whh1e, 4096L * 1024);
  k_cast_bf16<<<2048, 256, 0, stream>>>(dWhh0, Whh0d, 4096L * 1024);
  k_cast_bf16<<<2048, 256, 0, stream>>>(dWih1, Wih1d, 4096L * 1024);
  k_cast_bf16<<<2048, 256, 0, stream>>>(dWhh1, Whh1d, 4096L * 1024);
  k_cast_bf16<<<512, 256, 0, stream>>>(fc2_W, fc2Wb, 128L * 1024);
  k_prep_b0tot<<<16, 256, 0, stream>>>(d_b0, dWih0, fc2_b, b0dtot);
  k_fold_ih0<<<16, 256, 0, stream>>>(ibn_g, ibn_b, ibn_m, ibn_v, eWih0, e_b0, Wih0f, bias0f);
  k_fold_fc1<<<4, 256, 0, stream>>>(hbn_g, hbn_b, hbn_m, hbn_v, fc1_W, fc1_b,
                                    fbn_g, fbn_b, fbn_m, fbn_v, fc1Wf, fc1bf, fs2, fadd2);
  k_fold_wf<<<16384, 256, 0, stream>>>(dWih0, fc2_W, Wfold);

  k_enc<<<256, 256, 0, stream>>>(xb, Wih0f, Whh0e, Wih1e, Whh1e, bias0f, e_b1,
                                 h0_0, h0_1, h1_0, h1_1, c0b, c1b, flagsE);

  // enc finals: h0 in h0_1 (t=1023 odd), h1 in h1_1 (t=1024 even parity write)
  k_dec<<<256, 256, 0, stream>>>(Wfold, Whh0d, Wih1d, Whh1d, b0dtot, d_b0, d_b1,
                                 fc1Wf, fc1bf, fs2, fadd2, fc2Wb, fc2_b,
                                 h0_1, h1_1, f1b, c0b, c1b, pbuf0, pbuf1,
                                 out, flagsD);
}

// Round 5
// 62430.170 us; speedup vs baseline: 1.0074x; 1.0074x over previous
//
#include <hip/hip_runtime.h>
#include <hip/hip_bf16.h>

// LSTM_27144193311539: B=64,T=1024,D=128,H=1024,C=128. fp32 in/out.
// Round 11: R10 structure (4 single-matrix roles, 16 h-cols/WG, full-line
// pbuf) + R8-exact arithmetic: the pbuf partial is loaded FIRST and used as
// the MFMA C-in base, so each gate pre-activation reproduces R8's proven
// FP-op order (partial chain, then fresh segment chained on top). R9/R10's
// accuracy regression (1.95e-3 -> 6.8/7.8e-3) came from summing the fresh
// segment from zero and adding the partial afterward.
// Roles (64 WGs each, 16 h-cols, one K=1024 matrix in LDS, 129KB):
//   p1a (wg 0..63):    Wfold;  I1: pbuf0 C-in + f1b seg -> cell d0(t). I3: fc1.
//   p1b (wg 64..127):  Whh0d;  I2 (n<32) / I3 (n>=32): d0(t) seg -> pbuf0.
//                              wg 64..71 also run pred in I1.
//   p2a (wg 128..191): Wih1d;  I2: pbuf1 C-in + d0(t) seg -> cell d1(t).
//   p2b (wg 192..255): Whh1d;  I3: d1(t) seg -> pbuf1.
// pbuf layout: slot (g*256+tid)*4 floats -> each wave store/load touches
// contiguous 1KB full lines (R9 had 4x write-through amplification).

typedef __hip_bfloat16 hbf16;
typedef __bf16 bf16x8 __attribute__((ext_vector_type(8)));
typedef float f32x4 __attribute__((ext_vector_type(4)));
#define DEVI static __device__ __forceinline__

#define PITCH 2056   // enc LDS row pitch (elems) for K=2048
#define PITCH0 1160  // enc LDS row pitch for layer0 K=1152
#define PITCH1 1032  // dec LDS row pitch for K=1024

DEVI float sigf(float x) { return 1.0f / (1.0f + __expf(-x)); }

DEVI bf16x8 as_bf(f32x4 v) { union { f32x4 f; bf16x8 b; } u; u.f = v; return u.b; }

// ---- coherent store helpers (fire-and-forget; drained at barrier)
DEVI void st_u32_coh(void* p, unsigned int v) {
  __hip_atomic_store((unsigned int*)p, v, __ATOMIC_RELAXED, __HIP_MEMORY_SCOPE_AGENT);
}
DEVI void st_u64_coh(void* p, unsigned long long v) {
  __hip_atomic_store((unsigned long long*)p, v, __ATOMIC_RELAXED, __HIP_MEMORY_SCOPE_AGENT);
}
DEVI void st_f32_coh(float* p, float v) {
  __hip_atomic_store(p, v, __ATOMIC_RELAXED, __HIP_MEMORY_SCOPE_AGENT);
}
DEVI void st16_coh(float* p, f32x4 v) {
  asm volatile("global_store_dwordx4 %0, %1, off sc0 sc1"
               :: "v"(p), "v"(v) : "memory");
}
DEVI unsigned short bf_bits(float v) {
  union { __hip_bfloat16 b; unsigned short s; } u;
  u.b = __float2bfloat16(v);
  return u.s;
}

// ---- ONE asm block: 32 coherent 16B loads from ap (+64B steps) + wait.
DEVI void ld32_wait(f32x4* b, const hbf16* ap) {
  asm volatile(
    "global_load_dwordx4 %0, %32, off sc0 sc1\n\t"
    "global_load_dwordx4 %1, %32, off offset:64 sc0 sc1\n\t"
    "global_load_dwordx4 %2, %32, off offset:128 sc0 sc1\n\t"
    "global_load_dwordx4 %3, %32, off offset:192 sc0 sc1\n\t"
    "global_load_dwordx4 %4, %32, off offset:256 sc0 sc1\n\t"
    "global_load_dwordx4 %5, %32, off offset:320 sc0 sc1\n\t"
    "global_load_dwordx4 %6, %32, off offset:384 sc0 sc1\n\t"
    "global_load_dwordx4 %7, %32, off offset:448 sc0 sc1\n\t"
    "global_load_dwordx4 %8, %32, off offset:512 sc0 sc1\n\t"
    "global_load_dwordx4 %9, %32, off offset:576 sc0 sc1\n\t"
    "global_load_dwordx4 %10, %32, off offset:640 sc0 sc1\n\t"
    "global_load_dwordx4 %11, %32, off offset:704 sc0 sc1\n\t"
    "global_load_dwordx4 %12, %32, off offset:768 sc0 sc1\n\t"
    "global_load_dwordx4 %13, %32, off offset:832 sc0 sc1\n\t"
    "global_load_dwordx4 %14, %32, off offset:896 sc0 sc1\n\t"
    "global_load_dwordx4 %15, %32, off offset:960 sc0 sc1\n\t"
    "global_load_dwordx4 %16, %32, off offset:1024 sc0 sc1\n\t"
    "global_load_dwordx4 %17, %32, off offset:1088 sc0 sc1\n\t"
    "global_load_dwordx4 %18, %32, off offset:1152 sc0 sc1\n\t"
    "global_load_dwordx4 %19, %32, off offset:1216 sc0 sc1\n\t"
    "global_load_dwordx4 %20, %32, off offset:1280 sc0 sc1\n\t"
    "global_load_dwordx4 %21, %32, off offset:1344 sc0 sc1\n\t"
    "global_load_dwordx4 %22, %32, off offset:1408 sc0 sc1\n\t"
    "global_load_dwordx4 %23, %32, off offset:1472 sc0 sc1\n\t"
    "global_load_dwordx4 %24, %32, off offset:1536 sc0 sc1\n\t"
    "global_load_dwordx4 %25, %32, off offset:1600 sc0 sc1\n\t"
    "global_load_dwordx4 %26, %32, off offset:1664 sc0 sc1\n\t"
    "global_load_dwordx4 %27, %32, off offset:1728 sc0 sc1\n\t"
    "global_load_dwordx4 %28, %32, off offset:1792 sc0 sc1\n\t"
    "global_load_dwordx4 %29, %32, off offset:1856 sc0 sc1\n\t"
    "global_load_dwordx4 %30, %32, off offset:1920 sc0 sc1\n\t"
    "global_load_dwordx4 %31, %32, off offset:1984 sc0 sc1\n\t"
    "s_waitcnt vmcnt(0)"
    : "=&v"(b[0]), "=&v"(b[1]), "=&v"(b[2]), "=&v"(b[3]),
      "=&v"(b[4]), "=&v"(b[5]), "=&v"(b[6]), "=&v"(b[7]),
      "=&v"(b[8]), "=&v"(b[9]), "=&v"(b[10]), "=&v"(b[11]),
      "=&v"(b[12]), "=&v"(b[13]), "=&v"(b[14]), "=&v"(b[15]),
      "=&v"(b[16]), "=&v"(b[17]), "=&v"(b[18]), "=&v"(b[19]),
      "=&v"(b[20]), "=&v"(b[21]), "=&v"(b[22]), "=&v"(b[23]),
      "=&v"(b[24]), "=&v"(b[25]), "=&v"(b[26]), "=&v"(b[27]),
      "=&v"(b[28]), "=&v"(b[29]), "=&v"(b[30]), "=&v"(b[31])
    : "v"(ap) : "memory");
}

// ---- ONE asm block: 4 row-tiles x 8 coherent 16B loads + wait (fc1/pred).
DEVI void ld4x8_wait(f32x4* b, const hbf16* a0, const hbf16* a1,
                     const hbf16* a2, const hbf16* a3) {
  asm volatile(
    "global_load_dwordx4 %0, %32, off sc0 sc1\n\t"
    "global_load_dwordx4 %1, %32, off offset:64 sc0 sc1\n\t"
    "global_load_dwordx4 %2, %32, off offset:128 sc0 sc1\n\t"
    "global_load_dwordx4 %3, %32, off offset:192 sc0 sc1\n\t"
    "global_load_dwordx4 %4, %32, off offset:256 sc0 sc1\n\t"
    "global_load_dwordx4 %5, %32, off offset:320 sc0 sc1\n\t"
    "global_load_dwordx4 %6, %32, off offset:384 sc0 sc1\n\t"
    "global_load_dwordx4 %7, %32, off offset:448 sc0 sc1\n\t"
    "global_load_dwordx4 %8, %33, off sc0 sc1\n\t"
    "global_load_dwordx4 %9, %33, off offset:64 sc0 sc1\n\t"
    "global_load_dwordx4 %10, %33, off offset:128 sc0 sc1\n\t"
    "global_load_dwordx4 %11, %33, off offset:192 sc0 sc1\n\t"
    "global_load_dwordx4 %12, %33, off offset:256 sc0 sc1\n\t"
    "global_load_dwordx4 %13, %33, off offset:320 sc0 sc1\n\t"
    "global_load_dwordx4 %14, %33, off offset:384 sc0 sc1\n\t"
    "global_load_dwordx4 %15, %33, off offset:448 sc0 sc1\n\t"
    "global_load_dwordx4 %16, %34, off sc0 sc1\n\t"
    "global_load_dwordx4 %17, %34, off offset:64 sc0 sc1\n\t"
    "global_load_dwordx4 %18, %34, off offset:128 sc0 sc1\n\t"
    "global_load_dwordx4 %19, %34, off offset:192 sc0 sc1\n\t"
    "global_load_dwordx4 %20, %34, off offset:256 sc0 sc1\n\t"
    "global_load_dwordx4 %21, %34, off offset:320 sc0 sc1\n\t"
    "global_load_dwordx4 %22, %34, off offset:384 sc0 sc1\n\t"
    "global_load_dwordx4 %23, %34, off offset:448 sc0 sc1\n\t"
    "global_load_dwordx4 %24, %35, off sc0 sc1\n\t"
    "global_load_dwordx4 %25, %35, off offset:64 sc0 sc1\n\t"
    "global_load_dwordx4 %26, %35, off offset:128 sc0 sc1\n\t"
    "global_load_dwordx4 %27, %35, off offset:192 sc0 sc1\n\t"
    "global_load_dwordx4 %28, %35, off offset:256 sc0 sc1\n\t"
    "global_load_dwordx4 %29, %35, off offset:320 sc0 sc1\n\t"
    "global_load_dwordx4 %30, %35, off offset:384 sc0 sc1\n\t"
    "global_load_dwordx4 %31, %35, off offset:448 sc0 sc1\n\t"
    "s_waitcnt vmcnt(0)"
    : "=&v"(b[0]), "=&v"(b[1]), "=&v"(b[2]), "=&v"(b[3]),
      "=&v"(b[4]), "=&v"(b[5]), "=&v"(b[6]), "=&v"(b[7]),
      "=&v"(b[8]), "=&v"(b[9]), "=&v"(b[10]), "=&v"(b[11]),
      "=&v"(b[12]), "=&v"(b[13]), "=&v"(b[14]), "=&v"(b[15]),
      "=&v"(b[16]), "=&v"(b[17]), "=&v"(b[18]), "=&v"(b[19]),
      "=&v"(b[20]), "=&v"(b[21]), "=&v"(b[22]), "=&v"(b[23]),
      "=&v"(b[24]), "=&v"(b[25]), "=&v"(b[26]), "=&v"(b[27]),
      "=&v"(b[28]), "=&v"(b[29]), "=&v"(b[30]), "=&v"(b[31])
    : "v"(a0), "v"(a1), "v"(a2), "v"(a3) : "memory");
}

// ---- 4 coherent 16B loads from 4 independent pointers + wait.
DEVI void ld4p_wait(f32x4* b, const float* p0, const float* p1,
                    const float* p2, const float* p3) {
  asm volatile(
    "global_load_dwordx4 %0, %4, off sc0 sc1\n\t"
    "global_load_dwordx4 %1, %5, off sc0 sc1\n\t"
    "global_load_dwordx4 %2, %6, off sc0 sc1\n\t"
    "global_load_dwordx4 %3, %7, off sc0 sc1\n\t"
    "s_waitcnt vmcnt(0)"
    : "=&v"(b[0]), "=&v"(b[1]), "=&v"(b[2]), "=&v"(b[3])
    : "v"(p0), "v"(p1), "v"(p2), "v"(p3) : "memory");
}

// ---- grid barrier: vmcnt drain (coherent stores at MALL) + flag array.
DEVI void gbar(int* flags, int e) {
  asm volatile("s_waitcnt vmcnt(0) lgkmcnt(0)" ::: "memory");
  __syncthreads();
  if (threadIdx.x == 0)
    __hip_atomic_store(&flags[blockIdx.x], e, __ATOMIC_RELAXED, __HIP_MEMORY_SCOPE_AGENT);
  while (__hip_atomic_load(&flags[threadIdx.x], __ATOMIC_RELAXED,
                           __HIP_MEMORY_SCOPE_AGENT) < e)
    __builtin_amdgcn_s_sleep(1);
  __syncthreads();
}

// ---- cooperative LDS weight fill, enc variant (32 rows, 8 h-cols)
DEVI void fill_w(hbf16* W, int pitch, int koff, const hbf16* __restrict__ Wg,
                 int Kg, int base_h) {
  for (int r = (int)(threadIdx.x >> 3); r < 32; r += 32) {
    int g = r >> 3, hc = r & 7;
    const hbf16* src = Wg + (long)(g * 1024 + base_h + hc) * Kg;
    hbf16* dst = W + r * pitch + koff;
    for (int k = (threadIdx.x & 7) * 8; k < Kg; k += 64)
      *reinterpret_cast<bf16x8*>(dst + k) =
          *reinterpret_cast<const bf16x8*>(src + k);
  }
}

// ---- dec LDS weight fill: 64 rows (16 h-cols x 4 gates), K=1024
DEVI void fill_w16(hbf16* W, const hbf16* __restrict__ Wg, int base16) {
  int r = (int)(threadIdx.x >> 2);   // 64 rows, 4 threads/row
  int g = r >> 4, hc = r & 15;
  const hbf16* src = Wg + (long)(g * 1024 + base16 + hc) * 1024;
  hbf16* dst = W + r * PITCH1;
  for (int k = (threadIdx.x & 3) * 8; k < 1024; k += 32)
    *reinterpret_cast<bf16x8*>(dst + k) =
        *reinterpret_cast<const bf16x8*>(src + k);
}

// ---- enc coherent K=1024 gate-GEMM segment (2 accums, 8 h-cols)
DEVI void seg_asm(f32x4& a0, f32x4& a1, const hbf16* __restrict__ A, long lda,
                  const hbf16* W, int pitch, int koff, int w, int q, int r16) {
  const hbf16* ap = A + (long)(w * 16 + r16) * lda + q * 8;
  const hbf16* w0 = W + r16 * pitch + koff + q * 8;
  const hbf16* w1 = W + (16 + r16) * pitch + koff + q * 8;
  f32x4 b[32];
  ld32_wait(b, ap);
#pragma unroll
  for (int k = 0; k < 32; ++k) {
    bf16x8 av = as_bf(b[k]);
    bf16x8 b0 = *reinterpret_cast<const bf16x8*>(w0 + k * 32);
    bf16x8 b1 = *reinterpret_cast<const bf16x8*>(w1 + k * 32);
    a0 = __builtin_amdgcn_mfma_f32_16x16x32_bf16(av, b0, a0, 0, 0, 0);
    a1 = __builtin_amdgcn_mfma_f32_16x16x32_bf16(av, b1, a1, 0, 0, 0);
  }
}

// ---- dec coherent K=1024 segment: 4 gate accums (C-in chained), 16 h-cols.
DEVI void seg16(f32x4* a, const hbf16* __restrict__ A, const hbf16* W,
                int w, int q, int c) {
  const hbf16* ap = A + (long)(w * 16 + c) * 1024 + q * 8;
  const hbf16* w0 = W + c * PITCH1 + q * 8;
  const hbf16* w1 = W + (16 + c) * PITCH1 + q * 8;
  const hbf16* w2 = W + (32 + c) * PITCH1 + q * 8;
  const hbf16* w3 = W + (48 + c) * PITCH1 + q * 8;
  f32x4 b[32];
  ld32_wait(b, ap);
#pragma unroll
  for (int k = 0; k < 32; ++k) {
    bf16x8 av = as_bf(b[k]);
    a[0] = __builtin_amdgcn_mfma_f32_16x16x32_bf16(
        av, *reinterpret_cast<const bf16x8*>(w0 + k * 32), a[0], 0, 0, 0);
    a[1] = __builtin_amdgcn_mfma_f32_16x16x32_bf16(
        av, *reinterpret_cast<const bf16x8*>(w1 + k * 32), a[1], 0, 0, 0);
    a[2] = __builtin_amdgcn_mfma_f32_16x16x32_bf16(
        av, *reinterpret_cast<const bf16x8*>(w2 + k * 32), a[2], 0, 0, 0);
    a[3] = __builtin_amdgcn_mfma_f32_16x16x32_bf16(
        av, *reinterpret_cast<const bf16x8*>(w3 + k * 32), a[3], 0, 0, 0);
  }
}

// ---- plain K=128 segment (enc L0 x-input; read-only, normal caching)
DEVI void seg_x(f32x4& a0, f32x4& a1, const hbf16* __restrict__ A, long lda,
                const hbf16* W, int pitch, int w, int q, int r16) {
  const hbf16* ap = A + (long)(w * 16 + r16) * lda + q * 8;
  const hbf16* w0 = W + r16 * pitch + q * 8;
  const hbf16* w1 = W + (16 + r16) * pitch + q * 8;
#pragma unroll
  for (int k = 0; k < 128; k += 32) {
    bf16x8 av = *reinterpret_cast<const bf16x8*>(ap + k);
    bf16x8 b0 = *reinterpret_cast<const bf16x8*>(w0 + k);
    bf16x8 b1 = *reinterpret_cast<const bf16x8*>(w1 + k);
    a0 = __builtin_amdgcn_mfma_f32_16x16x32_bf16(av, b0, a0, 0, 0, 0);
    a1 = __builtin_amdgcn_mfma_f32_16x16x32_bf16(av, b1, a1, 0, 0, 0);
  }
}

// ---- 4-m-tile x K=256 slice GEMM (fc1 / pred): one batched round-trip.
DEVI void mm4_asm(f32x4* pa, const hbf16* __restrict__ abase, const bf16x8* fr) {
  f32x4 b[32];
  ld4x8_wait(b, abase, abase + 16384, abase + 32768, abase + 49152);
#pragma unroll
  for (int i = 0; i < 8; ++i)
#pragma unroll
    for (int mt = 0; mt < 4; ++mt)
      pa[mt] = __builtin_amdgcn_mfma_f32_16x16x32_bf16(
          as_bf(b[mt * 8 + i]), fr[i], pa[mt], 0, 0, 0);
}

// ---- enc LSTM cell (8-col packing, shfl-paired gates)
DEVI void cell(f32x4 a0, f32x4 a1, float bb0, float bb1, float* cst,
               hbf16* __restrict__ hout, int base_h, int lane, int w) {
  int q = lane >> 4, c = lane & 15;
#pragma unroll
  for (int r = 0; r < 4; ++r) {
    float z0 = a0[r] + bb0;
    float z1 = a1[r] + bb1;
    float zf = __shfl(z0, lane | 8, 64);
    float zo = __shfl(z1, lane | 8, 64);
    float hv = 0.f;
    if (c < 8) {
      float cn = sigf(zf) * cst[r] + sigf(z0) * tanhf(z1);
      cst[r] = cn;
      hv = sigf(zo) * tanhf(cn);
    }
    unsigned short my = bf_bits(hv);
    unsigned short nb = (unsigned short)__shfl((int)my, lane ^ 1, 64);
    if (c < 8 && (c & 1) == 0) {
      unsigned int pk = (unsigned int)my | ((unsigned int)nb << 16);
      st_u32_coh(hout + (long)(w * 16 + q * 4 + r) * 1024 + base_h + c, pk);
    }
  }
}

// ---- dec LSTM cell: 4 gate accums per lane, fully lane-local.
DEVI void cell16(const f32x4* a, const float* bb, float* cst,
                 hbf16* __restrict__ hout, int base16, int lane, int w) {
  int q = lane >> 4, c = lane & 15;
#pragma unroll
  for (int r = 0; r < 4; ++r) {
    float zi = a[0][r] + bb[0];
    float zf = a[1][r] + bb[1];
    float zg = a[2][r] + bb[2];
    float zo = a[3][r] + bb[3];
    float cn = sigf(zf) * cst[r] + sigf(zi) * tanhf(zg);
    cst[r] = cn;
    float hv = sigf(zo) * tanhf(cn);
    unsigned short my = bf_bits(hv);
    unsigned short nb = (unsigned short)__shfl((int)my, lane ^ 1, 64);
    if ((c & 1) == 0) {
      unsigned int pk = (unsigned int)my | ((unsigned int)nb << 16);
      st_u32_coh(hout + (long)(w * 16 + q * 4 + r) * 1024 + base16 + c, pk);
    }
  }
}

// ---- pbuf handoff, FULL-LINE layout: slot (g*256 + tid) * 4 floats.
DEVI void dump_partial(const f32x4* a, float* pb, int tid) {
#pragma unroll
  for (int g = 0; g < 4; ++g) st16_coh(pb + (g * 256 + tid) * 4, a[g]);
}

// load partial INTO a (used as MFMA C-in base -> R8-exact chaining)
DEVI void ld_partial(f32x4* a, const float* pb, int tid) {
  ld4p_wait(a, pb + (0 * 256 + tid) * 4, pb + (1 * 256 + tid) * 4,
            pb + (2 * 256 + tid) * 4, pb + (3 * 256 + tid) * 4);
}

DEVI void store_c(const float* cst, float* cbuf, int hcol_g, int lane, int w) {
  int q = lane >> 4, c = lane & 15;
  if (c < 8) {
#pragma unroll
    for (int r = 0; r < 4; ++r)
      st_f32_coh(&cbuf[(long)(w * 16 + q * 4 + r) * 1024 + hcol_g], cst[r]);
  }
}

// ================= encoder persistent kernel (R6 verbatim) =================
__global__ __launch_bounds__(256, 1) void k_enc(
    const hbf16* __restrict__ xb,
    const hbf16* __restrict__ Wih0f, const hbf16* __restrict__ Whh0,
    const hbf16* __restrict__ Wih1, const hbf16* __restrict__ Whh1,
    const float* __restrict__ b0f, const float* __restrict__ b1f,
    hbf16* h0_0, hbf16* h0_1, hbf16* h1_0, hbf16* h1_1,
    float* c0buf, float* c1buf, int* flags) {
  __shared__ hbf16 W[32 * PITCH];
  int wg = blockIdx.x, tid = threadIdx.x;
  int lane = tid & 63, w = tid >> 6, q = lane >> 4, c = lane & 15;
  bool isL0 = wg < 128;
  int cu = isL0 ? wg : wg - 128;
  int base_h = cu * 8;
  if (isL0) {
    fill_w(W, PITCH0, 0, Wih0f, 128, base_h);
    fill_w(W, PITCH0, 128, Whh0, 1024, base_h);
  } else {
    fill_w(W, PITCH, 0, Wih1, 1024, base_h);
    fill_w(W, PITCH, 1024, Whh1, 1024, base_h);
  }
  __syncthreads();
  const float* bias = isL0 ? b0f : b1f;
  float bb0 = bias[(c >> 3) * 1024 + base_h + (c & 7)];
  float bb1 = bias[(2 + (c >> 3)) * 1024 + base_h + (c & 7)];
  float cst[4] = {0.f, 0.f, 0.f, 0.f};
  int hcol_g = base_h + (c & 7);

  for (int t = 0; t <= 1024; ++t) {
    if (isL0) {
      if (t < 1024) {
        f32x4 a0 = {0.f,0.f,0.f,0.f}, a1 = {0.f,0.f,0.f,0.f};
        const hbf16* h0r = (t & 1) ? h0_0 : h0_1;   // h0(t-1)
        seg_asm(a0, a1, h0r, 1024L, W, PITCH0, 128, w, q, c);  // coherent first
        seg_x(a0, a1, xb + (long)t * 128, 131072L, W, PITCH0, w, q, c);
        hbf16* h0w = (t & 1) ? h0_1 : h0_0;         // h0(t)
        cell(a0, a1, bb0, bb1, cst, h0w, base_h, lane, w);
        if (t == 1023) store_c(cst, c0buf, hcol_g, lane, w);
      }
    } else {
      if (t >= 1) {   // computes h1(t-1)
        f32x4 a0 = {0.f,0.f,0.f,0.f}, a1 = {0.f,0.f,0.f,0.f};
        const hbf16* h0r = (t & 1) ? h0_0 : h0_1;   // h0(t-1)
        seg_asm(a0, a1, h0r, 1024L, W, PITCH, 0, w, q, c);
        const hbf16* h1r = (t & 1) ? h1_1 : h1_0;   // h1(t-2)
        seg_asm(a0, a1, h1r, 1024L, W, PITCH, 1024, w, q, c);
        hbf16* h1w = (t & 1) ? h1_0 : h1_1;         // h1(t-1)
        cell(a0, a1, bb0, bb1, cst, h1w, base_h, lane, w);
        if (t == 1024) store_c(cst, c1buf, hcol_g, lane, w);
      }
    }
    if (t < 1024) gbar(flags, t + 1);
  }
}

// ================= decoder persistent kernel =================
__global__ __launch_bounds__(256, 1) void k_dec(
    const hbf16* __restrict__ Wfold, const hbf16* __restrict__ Whh0d,
    const hbf16* __restrict__ Wih1d, const hbf16* __restrict__ Whh1d,
    const float* __restrict__ b0t, const float* __restrict__ b0p,
    const float* __restrict__ b1d,
    const hbf16* __restrict__ fc1Wf, const float* __restrict__ fc1bf,
    const float* __restrict__ fs2, const float* __restrict__ fadd2,
    const hbf16* __restrict__ fc2Wb, const float* __restrict__ fc2b,
    hbf16* d0, hbf16* d1, hbf16* f1b,
    const float* __restrict__ c0buf, const float* __restrict__ c1buf,
    float* pbuf0, float* pbuf1,
    float* __restrict__ out, int* flags) {
  __shared__ hbf16 W[64 * PITCH1];
  __shared__ float bounce[4][64][16];
  int wg = blockIdx.x, tid = threadIdx.x;
  int lane = tid & 63, w = tid >> 6, q = lane >> 4, c = lane & 15;
  int role = wg >> 6;          // 0=p1a(Wfold), 1=p1b(Whh0d), 2=p2a(Wih1d), 3=p2b(Whh1d)
  int n = wg & 63;
  int base16 = n * 16;
  {
    const hbf16* Wsrc = (role == 0) ? Wfold : (role == 1) ? Whh0d
                       : (role == 2) ? Wih1d : Whh1d;
    fill_w16(W, Wsrc, base16);
  }
  __syncthreads();
  // biases
  float bt[4] = {0,0,0,0}, bp[4] = {0,0,0,0};
  if (role == 0) {
#pragma unroll
    for (int g = 0; g < 4; ++g) {
      bt[g] = b0t[g * 1024 + base16 + c];
      bp[g] = b0p[g * 1024 + base16 + c];
    }
  } else if (role == 2) {
#pragma unroll
    for (int g = 0; g < 4; ++g) bt[g] = b1d[g * 1024 + base16 + c];
  }
  // cell-state handoff from encoder (plain cached loads, cross-kernel OK)
  float cst[4] = {0.f, 0.f, 0.f, 0.f};
  if (role == 0 || role == 2) {
    const float* cb = (role == 0) ? c0buf : c1buf;
#pragma unroll
    for (int r = 0; r < 4; ++r)
      cst[r] = cb[(long)(w * 16 + q * 4 + r) * 1024 + base16 + c];
  }
  // aux roles: fc1 on p1a (all 64); pred on first 8 of p1b
  bool isPred = (wg >= 64 && wg < 72);
  bf16x8 fr[8];
#pragma unroll
  for (int i = 0; i < 8; ++i) fr[i] = bf16x8{0,0,0,0,0,0,0,0};
  float e_b[4] = {0,0,0,0}, e_s[4] = {0,0,0,0}, e_a[4] = {0,0,0,0};
  int red_row = tid >> 2, red_c4 = (tid & 3) * 4;
  if (role == 0) {   // fc1 weights: 16 output cols n*16.., K-slice w*256
    const hbf16* fp = fc1Wf + (long)(n * 16 + c) * 1024 + w * 256 + q * 8;
#pragma unroll
    for (int i = 0; i < 8; ++i) fr[i] = *reinterpret_cast<const bf16x8*>(fp + i * 32);
#pragma unroll
    for (int i = 0; i < 4; ++i) {
      int col = n * 16 + red_c4 + i;
      e_b[i] = fc1bf[col]; e_s[i] = fs2[col]; e_a[i] = fadd2[col];
    }
  } else if (isPred) {
    const hbf16* fp = fc2Wb + (long)((wg - 64) * 16 + c) * 1024 + w * 256 + q * 8;
#pragma unroll
    for (int i = 0; i < 8; ++i) fr[i] = *reinterpret_cast<const bf16x8*>(fp + i * 32);
#pragma unroll
    for (int i = 0; i < 4; ++i) e_b[i] = fc2b[(wg - 64) * 16 + red_c4 + i];
  }

  // ---- pre-loop: partials from encoder finals (d0 = enc h0, d1 = enc h1)
  if (role == 1) {
    f32x4 a[4] = {{0,0,0,0},{0,0,0,0},{0,0,0,0},{0,0,0,0}};
    seg16(a, d0, W, w, q, c);
    dump_partial(a, pbuf0 + n * 4096, tid);
  } else if (role == 3) {
    f32x4 a[4] = {{0,0,0,0},{0,0,0,0},{0,0,0,0},{0,0,0,0}};
    seg16(a, d1, W, w, q, c);
    dump_partial(a, pbuf1 + n * 4096, tid);
  }
  gbar(flags, 1);

  for (int t = 0; t <= 1024; ++t) {
    // ---- interval 1: p1a gates d0(t) (partial C-in + f1b seg);
    //                  pred(t-1) on pred-WGs
    if (role == 0 && t < 1024) {
      f32x4 a[4];
      ld_partial(a, pbuf0 + n * 4096, tid);   // C-in base (R8 chaining)
      if (t > 0) seg16(a, f1b, W, w, q, c);
      cell16(a, (t > 0) ? bt : bp, cst, d0, base16, lane, w);
    }
    if (isPred && t >= 1) {   // pred(t-1) = f1(t-1)@fc2^T + fc2_b -> out
      f32x4 pa[4] = {{0,0,0,0},{0,0,0,0},{0,0,0,0},{0,0,0,0}};
      mm4_asm(pa, f1b + (long)c * 1024 + w * 256 + q * 8, fr);
#pragma unroll
      for (int mt = 0; mt < 4; ++mt)
#pragma unroll
        for (int r = 0; r < 4; ++r) bounce[w][mt * 16 + q * 4 + r][c] = pa[mt][r];
      __syncthreads();
#pragma unroll
      for (int i = 0; i < 4; ++i) {
        int cc = red_c4 + i;
        float s = bounce[0][red_row][cc] + bounce[1][red_row][cc] +
                  bounce[2][red_row][cc] + bounce[3][red_row][cc] + e_b[i];
        out[(long)red_row * 131072 + (long)(t - 1) * 128 + (wg - 64) * 16 + cc] = s;
      }
    }
    if (t == 1024) break;
    gbar(flags, 3 * t + 2);
    // ---- interval 2: p2a gates d1(t) (partial C-in + d0(t) seg);
    //                  p1b first half -> pbuf0 for t+1
    if (role == 2) {
      f32x4 a[4];
      ld_partial(a, pbuf1 + n * 4096, tid);   // C-in base (R8 chaining)
      seg16(a, d0, W, w, q, c);
      cell16(a, bt, cst, d1, base16, lane, w);
    } else if (role == 1 && n < 32 && t < 1023) {
      f32x4 a[4] = {{0,0,0,0},{0,0,0,0},{0,0,0,0},{0,0,0,0}};
      seg16(a, d0, W, w, q, c);
      dump_partial(a, pbuf0 + n * 4096, tid);
    }
    gbar(flags, 3 * t + 3);
    // ---- interval 3: p1a: fc1 -> f1(t); p1b second half -> pbuf0;
    //                  p2b -> pbuf1 for t+1
    if (role == 0) {
      f32x4 pa[4] = {{0,0,0,0},{0,0,0,0},{0,0,0,0},{0,0,0,0}};
      mm4_asm(pa, d1 + (long)c * 1024 + w * 256 + q * 8, fr);
#pragma unroll
      for (int mt = 0; mt < 4; ++mt)
#pragma unroll
        for (int r = 0; r < 4; ++r) bounce[w][mt * 16 + q * 4 + r][c] = pa[mt][r];
      __syncthreads();
#pragma unroll
      for (int i = 0; i < 4; ++i) {
        int cc = red_c4 + i;
        float s = bounce[0][red_row][cc] + bounce[1][red_row][cc] +
                  bounce[2][red_row][cc] + bounce[3][red_row][cc];
        float v = fmaxf((s + e_b[i]) * e_s[i] + e_a[i], 0.f);
        bounce[0][red_row][cc] = v;   // stage for packed store
      }
      {
        union { unsigned short s4[4]; unsigned long long u; } pk;
#pragma unroll
        for (int i = 0; i < 4; ++i) pk.s4[i] = bf_bits(bounce[0][red_row][red_c4 + i]);
        st_u64_coh(f1b + (long)red_row * 1024 + n * 16 + red_c4, pk.u);
      }
    } else if (role == 1 && n >= 32 && t < 1023) {
      f32x4 a[4] = {{0,0,0,0},{0,0,0,0},{0,0,0,0},{0,0,0,0}};
      seg16(a, d0, W, w, q, c);
      dump_partial(a, pbuf0 + n * 4096, tid);
    } else if (role == 3 && t < 1023) {
      f32x4 a[4] = {{0,0,0,0},{0,0,0,0},{0,0,0,0},{0,0,0,0}};
      seg16(a, d1, W, w, q, c);
      dump_partial(a, pbuf1 + n * 4096, tid);
    }
    gbar(flags, 3 * t + 4);
  }
}

// ================= prep kernels (verified in R2) =================

__global__ void k_cast_bf16(const float* __restrict__ s, hbf16* __restrict__ d, long n) {
  long i = (long)blockIdx.x * blockDim.x + threadIdx.x;
  long stride = (long)gridDim.x * blockDim.x;
  for (; i < n; i += stride) d[i] = __float2bfloat16(s[i]);
}

__global__ void k_prep_b0tot(const float* __restrict__ dec_b0, const float* __restrict__ dWih0,
                             const float* __restrict__ fc2b, float* __restrict__ b0d_tot) {
  int n = blockIdx.x * 256 + threadIdx.x;
  float acc = 0.f;
  for (int cc = 0; cc < 128; ++cc) acc += dWih0[n * 128 + cc] * fc2b[cc];
  b0d_tot[n] = dec_b0[n] + acc;
}

__global__ void k_fold_ih0(const float* __restrict__ g, const float* __restrict__ bb,
                           const float* __restrict__ m, const float* __restrict__ v,
                           const float* __restrict__ Wm, const float* __restrict__ b0,
                           hbf16* __restrict__ Wf, float* __restrict__ biasf) {
  int n = blockIdx.x * 256 + threadIdx.x;
  float acc = 0.f;
  for (int k = 0; k < 128; ++k) {
    float s = g[k] * rsqrtf(v[k] + 1e-5f);
    float tt = bb[k] - m[k] * s;
    float wv = Wm[n * 128 + k];
    Wf[n * 128 + k] = __float2bfloat16(wv * s);
    acc += tt * wv;
  }
  biasf[n] = b0[n] + acc;
}

__global__ void k_fold_fc1(const float* __restrict__ hg, const float* __restrict__ hb,
                           const float* __restrict__ hm, const float* __restrict__ hv,
                           const float* __restrict__ Wm, const float* __restrict__ fb,
                           const float* __restrict__ fg, const float* __restrict__ fbb,
                           const float* __restrict__ fm, const float* __restrict__ fv,
                           hbf16* __restrict__ Wf, float* __restrict__ bfo,
                           float* __restrict__ fs2, float* __restrict__ fadd2) {
  int n = blockIdx.x * 256 + threadIdx.x;
  float acc = 0.f;
  for (int k = 0; k < 1024; ++k) {
    float s = hg[k] * rsqrtf(hv[k] + 1e-5f);
    float tt = hb[k] - hm[k] * s;
    float wv = Wm[(long)n * 1024 + k];
    Wf[(long)n * 1024 + k] = __float2bfloat16(wv * s);
    acc += tt * wv;
  }
  bfo[n] = fb[n] + acc;
  float s2 = fg[n] * rsqrtf(fv[n] + 1e-5f);
  fs2[n] = s2;
  fadd2[n] = fbb[n] - fm[n] * s2;
}

__global__ void k_fold_wf(const float* __restrict__ Wih0d, const float* __restrict__ fc2W,
                          hbf16* __restrict__ Wfold) {
  long gid = (long)blockIdx.x * 256 + threadIdx.x;
  int n = (int)(gid >> 10), jcol = (int)(gid & 1023);
  float acc = 0.f;
  for (int cc = 0; cc < 128; ++cc)
    acc += Wih0d[n * 128 + cc] * fc2W[cc * 1024 + jcol];
  Wfold[gid] = __float2bfloat16(acc);
}

// ================= host =================

extern "C" void kernel_launch(void* const* d_in, const int* in_sizes, int n_in,
                              void* d_out, int out_size, void* d_ws, size_t ws_size,
                              hipStream_t stream) {
  (void)in_sizes; (void)n_in; (void)out_size; (void)ws_size;
  const float* x     = (const float*)d_in[0];
  const float* ibn_g = (const float*)d_in[1];
  const float* ibn_b = (const float*)d_in[2];
  const float* ibn_m = (const float*)d_in[3];
  const float* ibn_v = (const float*)d_in[4];
  const float* eWih0 = (const float*)d_in[5];
  const float* eWhh0 = (const float*)d_in[6];
  const float* e_b0  = (const float*)d_in[7];
  const float* eWih1 = (const float*)d_in[8];
  const float* eWhh1 = (const float*)d_in[9];
  const float* e_b1  = (const float*)d_in[10];
  const float* dWih0 = (const float*)d_in[11];
  const float* dWhh0 = (const float*)d_in[12];
  const float* d_b0  = (const float*)d_in[13];
  const float* dWih1 = (const float*)d_in[14];
  const float* dWhh1 = (const float*)d_in[15];
  const float* d_b1  = (const float*)d_in[16];
  const float* hbn_g = (const float*)d_in[17];
  const float* hbn_b = (const float*)d_in[18];
  const float* hbn_m = (const float*)d_in[19];
  const float* hbn_v = (const float*)d_in[20];
  const float* fc1_W = (const float*)d_in[21];
  const float* fc1_b = (const float*)d_in[22];
  const float* fbn_g = (const float*)d_in[23];
  const float* fbn_b = (const float*)d_in[24];
  const float* fbn_m = (const float*)d_in[25];
  const float* fbn_v = (const float*)d_in[26];
  const float* fc2_W = (const float*)d_in[27];
  const float* fc2_b = (const float*)d_in[28];
  float* out = (float*)d_out;

  char* p = (char*)d_ws;
  auto alloc = [&](size_t bytes) -> void* {
    void* r = (void*)p;
    p += (bytes + 255) & ~(size_t)255;
    return r;
  };
  hbf16* xb     = (hbf16*)alloc(64L * 1024 * 128 * 2);
  hbf16* Wih0f  = (hbf16*)alloc(4096L * 128 * 2);
  hbf16* Whh0e  = (hbf16*)alloc(4096L * 1024 * 2);
  hbf16* Wih1e  = (hbf16*)alloc(4096L * 1024 * 2);
  hbf16* Whh1e  = (hbf16*)alloc(4096L * 1024 * 2);
  hbf16* Wfold  = (hbf16*)alloc(4096L * 1024 * 2);
  hbf16* Whh0d  = (hbf16*)alloc(4096L * 1024 * 2);
  hbf16* Wih1d  = (hbf16*)alloc(4096L * 1024 * 2);
  hbf16* Whh1d  = (hbf16*)alloc(4096L * 1024 * 2);
  hbf16* fc1Wf  = (hbf16*)alloc(1024L * 1024 * 2);
  hbf16* fc2Wb  = (hbf16*)alloc(128L * 1024 * 2);
  float* bias0f = (float*)alloc(4096 * 4);
  float* b0dtot = (float*)alloc(4096 * 4);
  float* fc1bf  = (float*)alloc(1024 * 4);
  float* fs2    = (float*)alloc(1024 * 4);
  float* fadd2  = (float*)alloc(1024 * 4);
  float* pbuf0  = (float*)alloc(64L * 4096 * 4);
  float* pbuf1  = (float*)alloc(64L * 4096 * 4);
  char* st = p;  // zero-init region
  hbf16* h0_0 = (hbf16*)alloc(64L * 1024 * 2);
  hbf16* h0_1 = (hbf16*)alloc(64L * 1024 * 2);
  hbf16* h1_0 = (hbf16*)alloc(64L * 1024 * 2);
  hbf16* h1_1 = (hbf16*)alloc(64L * 1024 * 2);
  float* c0b  = (float*)alloc(64L * 1024 * 4);
  float* c1b  = (float*)alloc(64L * 1024 * 4);
  hbf16* f1b  = (hbf16*)alloc(64L * 1024 * 2);
  int*   flagsE = (int*)alloc(256 * 4);
  int*   flagsD = (int*)alloc(256 * 4);
  size_t stbytes = (size_t)(p - st);

  hipMemsetAsync(st, 0, stbytes, stream);

  k_cast_bf16<<<4096, 256, 0, stream>>>(x, xb, 64L * 1024 * 128);
  k_cast_bf16<<<2048, 256, 0, stream>>>(eWhh0, Whh0e, 4096L * 1024);
  k_cast_bf16<<<2048, 256, 0, stream>>>(eWih1, Wih1e, 4096L * 1024);
  k_cast_bf16<<<2048, 256, 0, stream>>>(eWhh1, Whh1e, 4096L * 1024);
  k_cast_bf16<<<2048, 256, 0, stream>>>(dWhh0, Whh0d, 4096L * 1024);
  k_cast_bf16<<<2048, 256, 0, stream>>>(dWih1, Wih1d, 4096L * 1024);
  k_cast_bf16<<<2048, 256, 0, stream>>>(dWhh1, Whh1d, 4096L * 1024);
  k_cast_bf16<<<512, 256, 0, stream>>>(fc2_W, fc2Wb, 128L * 1024);
  k_prep_b0tot<<<16, 256, 0, stream>>>(d_b0, dWih0, fc2_b, b0dtot);
  k_fold_ih0<<<16, 256, 0, stream>>>(ibn_g, ibn_b, ibn_m, ibn_v, eWih0, e_b0, Wih0f, bias0f);
  k_fold_fc1<<<4, 256, 0, stream>>>(hbn_g, hbn_b, hbn_m, hbn_v, fc1_W, fc1_b,
                                    fbn_g, fbn_b, fbn_m, fbn_v, fc1Wf, fc1bf, fs2, fadd2);
  k_fold_wf<<<16384, 256, 0, stream>>>(dWih0, fc2_W, Wfold);

  k_enc<<<256, 256, 0, stream>>>(xb, Wih0f, Whh0e, Wih1e, Whh1e, bias0f, e_b1,
                                 h0_0, h0_1, h1_0, h1_1, c0b, c1b, flagsE);

  // enc finals: h0 in h0_1 (t=1023 odd), h1 in h1_1 (t=1024 even parity write)
  k_dec<<<256, 256, 0, stream>>>(Wfold, Whh0d, Wih1d, Whh1d, b0dtot, d_b0, d_b1,
                                 fc1Wf, fc1bf, fs2, fadd2, fc2Wb, fc2_b,
                                 h0_1, h1_1, f1b, c0b, c1b, pbuf0, pbuf1,
                                 out, flagsD);
}

// Round 6
// 39165.594 us; speedup vs baseline: 1.6058x; 1.5940x over previous
//
#include <hip/hip_runtime.h>
#include <hip/hip_bf16.h>

// LSTM_27144193311539: B=64,T=1024,D=128,H=1024,C=128. fp32 in/out.
// Round 12: R8 base (proven 47.2ms total, absmax 1.95e-3) with ONE change:
// sharded atomic-counter grid barrier. Old gbar had 256 threads x 256 WGs
// = 65536 concurrent MALL flag-pollers -- idle-WG poll traffic competes
// with working WGs' coherent segment reads at the TCCs, inflating both
// barrier latency and seg time. New gbar: thread0 atomicAdd to shard
// (wg&7) (32 arrivals/shard/epoch), only threads 0..7 poll (one shard
// each), rest park at __syncthreads. Poll streams 65536 -> 2048.
// Everything else is R8 verbatim (recurrent-partial pipelining in regs):
//   I1: p1 f1b-seg + held partial -> cell d0(t); pred mm4.
//   I2: p2 d0-seg + held partial -> cell d1(t); p1/P3-half d0r partial.
//   I3: p3 fc1 mm4 -> f1(t); p1-rest d0r partial; p2 d1r partial.

typedef __hip_bfloat16 hbf16;
typedef __bf16 bf16x8 __attribute__((ext_vector_type(8)));
typedef float f32x4 __attribute__((ext_vector_type(4)));
#define DEVI static __device__ __forceinline__

#define PITCH 2056   // LDS row pitch (elems) for K=2048
#define PITCH0 1160  // LDS row pitch for enc layer0 K=1152

DEVI float sigf(float x) { return 1.0f / (1.0f + __expf(-x)); }

DEVI bf16x8 as_bf(f32x4 v) { union { f32x4 f; bf16x8 b; } u; u.f = v; return u.b; }

// ---- coherent store helpers (fire-and-forget; drained at barrier)
DEVI void st_u32_coh(void* p, unsigned int v) {
  __hip_atomic_store((unsigned int*)p, v, __ATOMIC_RELAXED, __HIP_MEMORY_SCOPE_AGENT);
}
DEVI void st_u64_coh(void* p, unsigned long long v) {
  __hip_atomic_store((unsigned long long*)p, v, __ATOMIC_RELAXED, __HIP_MEMORY_SCOPE_AGENT);
}
DEVI void st_f32_coh(float* p, float v) {
  __hip_atomic_store(p, v, __ATOMIC_RELAXED, __HIP_MEMORY_SCOPE_AGENT);
}
DEVI unsigned short bf_bits(float v) {
  union { __hip_bfloat16 b; unsigned short s; } u;
  u.b = __float2bfloat16(v);
  return u.s;
}

// ---- ONE asm block: 32 coherent 16B loads from ap (+64B steps) + wait.
DEVI void ld32_wait(f32x4* b, const hbf16* ap) {
  asm volatile(
    "global_load_dwordx4 %0, %32, off sc0 sc1\n\t"
    "global_load_dwordx4 %1, %32, off offset:64 sc0 sc1\n\t"
    "global_load_dwordx4 %2, %32, off offset:128 sc0 sc1\n\t"
    "global_load_dwordx4 %3, %32, off offset:192 sc0 sc1\n\t"
    "global_load_dwordx4 %4, %32, off offset:256 sc0 sc1\n\t"
    "global_load_dwordx4 %5, %32, off offset:320 sc0 sc1\n\t"
    "global_load_dwordx4 %6, %32, off offset:384 sc0 sc1\n\t"
    "global_load_dwordx4 %7, %32, off offset:448 sc0 sc1\n\t"
    "global_load_dwordx4 %8, %32, off offset:512 sc0 sc1\n\t"
    "global_load_dwordx4 %9, %32, off offset:576 sc0 sc1\n\t"
    "global_load_dwordx4 %10, %32, off offset:640 sc0 sc1\n\t"
    "global_load_dwordx4 %11, %32, off offset:704 sc0 sc1\n\t"
    "global_load_dwordx4 %12, %32, off offset:768 sc0 sc1\n\t"
    "global_load_dwordx4 %13, %32, off offset:832 sc0 sc1\n\t"
    "global_load_dwordx4 %14, %32, off offset:896 sc0 sc1\n\t"
    "global_load_dwordx4 %15, %32, off offset:960 sc0 sc1\n\t"
    "global_load_dwordx4 %16, %32, off offset:1024 sc0 sc1\n\t"
    "global_load_dwordx4 %17, %32, off offset:1088 sc0 sc1\n\t"
    "global_load_dwordx4 %18, %32, off offset:1152 sc0 sc1\n\t"
    "global_load_dwordx4 %19, %32, off offset:1216 sc0 sc1\n\t"
    "global_load_dwordx4 %20, %32, off offset:1280 sc0 sc1\n\t"
    "global_load_dwordx4 %21, %32, off offset:1344 sc0 sc1\n\t"
    "global_load_dwordx4 %22, %32, off offset:1408 sc0 sc1\n\t"
    "global_load_dwordx4 %23, %32, off offset:1472 sc0 sc1\n\t"
    "global_load_dwordx4 %24, %32, off offset:1536 sc0 sc1\n\t"
    "global_load_dwordx4 %25, %32, off offset:1600 sc0 sc1\n\t"
    "global_load_dwordx4 %26, %32, off offset:1664 sc0 sc1\n\t"
    "global_load_dwordx4 %27, %32, off offset:1728 sc0 sc1\n\t"
    "global_load_dwordx4 %28, %32, off offset:1792 sc0 sc1\n\t"
    "global_load_dwordx4 %29, %32, off offset:1856 sc0 sc1\n\t"
    "global_load_dwordx4 %30, %32, off offset:1920 sc0 sc1\n\t"
    "global_load_dwordx4 %31, %32, off offset:1984 sc0 sc1\n\t"
    "s_waitcnt vmcnt(0)"
    : "=&v"(b[0]), "=&v"(b[1]), "=&v"(b[2]), "=&v"(b[3]),
      "=&v"(b[4]), "=&v"(b[5]), "=&v"(b[6]), "=&v"(b[7]),
      "=&v"(b[8]), "=&v"(b[9]), "=&v"(b[10]), "=&v"(b[11]),
      "=&v"(b[12]), "=&v"(b[13]), "=&v"(b[14]), "=&v"(b[15]),
      "=&v"(b[16]), "=&v"(b[17]), "=&v"(b[18]), "=&v"(b[19]),
      "=&v"(b[20]), "=&v"(b[21]), "=&v"(b[22]), "=&v"(b[23]),
      "=&v"(b[24]), "=&v"(b[25]), "=&v"(b[26]), "=&v"(b[27]),
      "=&v"(b[28]), "=&v"(b[29]), "=&v"(b[30]), "=&v"(b[31])
    : "v"(ap) : "memory");
}

// ---- ONE asm block: 4 row-tiles x 8 coherent 16B loads + wait (fc1/pred).
DEVI void ld4x8_wait(f32x4* b, const hbf16* a0, const hbf16* a1,
                     const hbf16* a2, const hbf16* a3) {
  asm volatile(
    "global_load_dwordx4 %0, %32, off sc0 sc1\n\t"
    "global_load_dwordx4 %1, %32, off offset:64 sc0 sc1\n\t"
    "global_load_dwordx4 %2, %32, off offset:128 sc0 sc1\n\t"
    "global_load_dwordx4 %3, %32, off offset:192 sc0 sc1\n\t"
    "global_load_dwordx4 %4, %32, off offset:256 sc0 sc1\n\t"
    "global_load_dwordx4 %5, %32, off offset:320 sc0 sc1\n\t"
    "global_load_dwordx4 %6, %32, off offset:384 sc0 sc1\n\t"
    "global_load_dwordx4 %7, %32, off offset:448 sc0 sc1\n\t"
    "global_load_dwordx4 %8, %33, off sc0 sc1\n\t"
    "global_load_dwordx4 %9, %33, off offset:64 sc0 sc1\n\t"
    "global_load_dwordx4 %10, %33, off offset:128 sc0 sc1\n\t"
    "global_load_dwordx4 %11, %33, off offset:192 sc0 sc1\n\t"
    "global_load_dwordx4 %12, %33, off offset:256 sc0 sc1\n\t"
    "global_load_dwordx4 %13, %33, off offset:320 sc0 sc1\n\t"
    "global_load_dwordx4 %14, %33, off offset:384 sc0 sc1\n\t"
    "global_load_dwordx4 %15, %33, off offset:448 sc0 sc1\n\t"
    "global_load_dwordx4 %16, %34, off sc0 sc1\n\t"
    "global_load_dwordx4 %17, %34, off offset:64 sc0 sc1\n\t"
    "global_load_dwordx4 %18, %34, off offset:128 sc0 sc1\n\t"
    "global_load_dwordx4 %19, %34, off offset:192 sc0 sc1\n\t"
    "global_load_dwordx4 %20, %34, off offset:256 sc0 sc1\n\t"
    "global_load_dwordx4 %21, %34, off offset:320 sc0 sc1\n\t"
    "global_load_dwordx4 %22, %34, off offset:384 sc0 sc1\n\t"
    "global_load_dwordx4 %23, %34, off offset:448 sc0 sc1\n\t"
    "global_load_dwordx4 %24, %35, off sc0 sc1\n\t"
    "global_load_dwordx4 %25, %35, off offset:64 sc0 sc1\n\t"
    "global_load_dwordx4 %26, %35, off offset:128 sc0 sc1\n\t"
    "global_load_dwordx4 %27, %35, off offset:192 sc0 sc1\n\t"
    "global_load_dwordx4 %28, %35, off offset:256 sc0 sc1\n\t"
    "global_load_dwordx4 %29, %35, off offset:320 sc0 sc1\n\t"
    "global_load_dwordx4 %30, %35, off offset:384 sc0 sc1\n\t"
    "global_load_dwordx4 %31, %35, off offset:448 sc0 sc1\n\t"
    "s_waitcnt vmcnt(0)"
    : "=&v"(b[0]), "=&v"(b[1]), "=&v"(b[2]), "=&v"(b[3]),
      "=&v"(b[4]), "=&v"(b[5]), "=&v"(b[6]), "=&v"(b[7]),
      "=&v"(b[8]), "=&v"(b[9]), "=&v"(b[10]), "=&v"(b[11]),
      "=&v"(b[12]), "=&v"(b[13]), "=&v"(b[14]), "=&v"(b[15]),
      "=&v"(b[16]), "=&v"(b[17]), "=&v"(b[18]), "=&v"(b[19]),
      "=&v"(b[20]), "=&v"(b[21]), "=&v"(b[22]), "=&v"(b[23]),
      "=&v"(b[24]), "=&v"(b[25]), "=&v"(b[26]), "=&v"(b[27]),
      "=&v"(b[28]), "=&v"(b[29]), "=&v"(b[30]), "=&v"(b[31])
    : "v"(a0), "v"(a1), "v"(a2), "v"(a3) : "memory");
}

// ---- grid barrier: vmcnt drain + SHARDED atomic counter (8 lines).
// Arrival: thread0 atomicAdd to shard (wg&7) -> exactly 32 arrivals/shard
// per epoch. Wait: threads 0..7 poll one shard each (2048 poll streams
// chip-wide instead of 65536); the rest park at __syncthreads.
DEVI void gbar(int* cnt8, int e) {
  asm volatile("s_waitcnt vmcnt(0) lgkmcnt(0)" ::: "memory");
  __syncthreads();
  if (threadIdx.x == 0)
    __hip_atomic_fetch_add(&cnt8[(blockIdx.x & 7) * 16], 1,
                           __ATOMIC_RELAXED, __HIP_MEMORY_SCOPE_AGENT);
  if (threadIdx.x < 8) {
    while (__hip_atomic_load(&cnt8[threadIdx.x * 16], __ATOMIC_RELAXED,
                             __HIP_MEMORY_SCOPE_AGENT) < e * 32)
      __builtin_amdgcn_s_sleep(1);
  }
  __syncthreads();
}

// ---- cooperative LDS weight fill (plain cached loads: read-only inputs)
DEVI void fill_w(hbf16* W, int pitch, int koff, const hbf16* __restrict__ Wg,
                 int Kg, int base_h) {
  for (int r = (int)(threadIdx.x >> 3); r < 32; r += 32) {
    int g = r >> 3, hc = r & 7;
    const hbf16* src = Wg + (long)(g * 1024 + base_h + hc) * Kg;
    hbf16* dst = W + r * pitch + koff;
    for (int k = (threadIdx.x & 7) * 8; k < Kg; k += 64)
      *reinterpret_cast<bf16x8*>(dst + k) =
          *reinterpret_cast<const bf16x8*>(src + k);
  }
}

// ---- coherent K=1024 gate-GEMM segment: one batched round-trip, then MFMA.
DEVI void seg_asm(f32x4& a0, f32x4& a1, const hbf16* __restrict__ A, long lda,
                  const hbf16* W, int pitch, int koff, int w, int q, int r16) {
  const hbf16* ap = A + (long)(w * 16 + r16) * lda + q * 8;
  const hbf16* w0 = W + r16 * pitch + koff + q * 8;
  const hbf16* w1 = W + (16 + r16) * pitch + koff + q * 8;
  f32x4 b[32];
  ld32_wait(b, ap);
#pragma unroll
  for (int k = 0; k < 32; ++k) {
    bf16x8 av = as_bf(b[k]);
    bf16x8 b0 = *reinterpret_cast<const bf16x8*>(w0 + k * 32);
    bf16x8 b1 = *reinterpret_cast<const bf16x8*>(w1 + k * 32);
    a0 = __builtin_amdgcn_mfma_f32_16x16x32_bf16(av, b0, a0, 0, 0, 0);
    a1 = __builtin_amdgcn_mfma_f32_16x16x32_bf16(av, b1, a1, 0, 0, 0);
  }
}

// ---- plain K=128 segment (enc L0 x-input; read-only, normal caching)
DEVI void seg_x(f32x4& a0, f32x4& a1, const hbf16* __restrict__ A, long lda,
                const hbf16* W, int pitch, int w, int q, int r16) {
  const hbf16* ap = A + (long)(w * 16 + r16) * lda + q * 8;
  const hbf16* w0 = W + r16 * pitch + q * 8;
  const hbf16* w1 = W + (16 + r16) * pitch + q * 8;
#pragma unroll
  for (int k = 0; k < 128; k += 32) {
    bf16x8 av = *reinterpret_cast<const bf16x8*>(ap + k);
    bf16x8 b0 = *reinterpret_cast<const bf16x8*>(w0 + k);
    bf16x8 b1 = *reinterpret_cast<const bf16x8*>(w1 + k);
    a0 = __builtin_amdgcn_mfma_f32_16x16x32_bf16(av, b0, a0, 0, 0, 0);
    a1 = __builtin_amdgcn_mfma_f32_16x16x32_bf16(av, b1, a1, 0, 0, 0);
  }
}

// ---- 4-m-tile x K=256 slice GEMM (fc1 / pred): one batched round-trip.
DEVI void mm4_asm(f32x4* pa, const hbf16* __restrict__ abase, const bf16x8* fr) {
  f32x4 b[32];
  ld4x8_wait(b, abase, abase + 16384, abase + 32768, abase + 49152);
#pragma unroll
  for (int i = 0; i < 8; ++i)
#pragma unroll
    for (int mt = 0; mt < 4; ++mt)
      pa[mt] = __builtin_amdgcn_mfma_f32_16x16x32_bf16(
          as_bf(b[mt * 8 + i]), fr[i], pa[mt], 0, 0, 0);
}

// ---- LSTM cell. acc0 cols 0..7=gate i, 8..15=f; acc1: g / o.
DEVI void cell(f32x4 a0, f32x4 a1, float bb0, float bb1, float* cst,
               hbf16* __restrict__ hout, int base_h, int lane, int w) {
  int q = lane >> 4, c = lane & 15;
#pragma unroll
  for (int r = 0; r < 4; ++r) {
    float z0 = a0[r] + bb0;
    float z1 = a1[r] + bb1;
    float zf = __shfl(z0, lane | 8, 64);
    float zo = __shfl(z1, lane | 8, 64);
    float hv = 0.f;
    if (c < 8) {
      float cn = sigf(zf) * cst[r] + sigf(z0) * tanhf(z1);
      cst[r] = cn;
      hv = sigf(zo) * tanhf(cn);
    }
    unsigned short my = bf_bits(hv);
    unsigned short nb = (unsigned short)__shfl((int)my, lane ^ 1, 64);
    if (c < 8 && (c & 1) == 0) {
      unsigned int pk = (unsigned int)my | ((unsigned int)nb << 16);
      st_u32_coh(hout + (long)(w * 16 + q * 4 + r) * 1024 + base_h + c, pk);
    }
  }
}

DEVI void store_c(const float* cst, float* cbuf, int hcol_g, int lane, int w) {
  int q = lane >> 4, c = lane & 15;
  if (c < 8) {
#pragma unroll
    for (int r = 0; r < 4; ++r)
      st_f32_coh(&cbuf[(long)(w * 16 + q * 4 + r) * 1024 + hcol_g], cst[r]);
  }
}

// ================= encoder persistent kernel =================
__global__ __launch_bounds__(256, 1) void k_enc(
    const hbf16* __restrict__ xb,
    const hbf16* __restrict__ Wih0f, const hbf16* __restrict__ Whh0,
    const hbf16* __restrict__ Wih1, const hbf16* __restrict__ Whh1,
    const float* __restrict__ b0f, const float* __restrict__ b1f,
    hbf16* h0_0, hbf16* h0_1, hbf16* h1_0, hbf16* h1_1,
    float* c0buf, float* c1buf, int* flags) {
  __shared__ hbf16 W[32 * PITCH];
  int wg = blockIdx.x, tid = threadIdx.x;
  int lane = tid & 63, w = tid >> 6, q = lane >> 4, c = lane & 15;
  bool isL0 = wg < 128;
  int cu = isL0 ? wg : wg - 128;
  int base_h = cu * 8;
  if (isL0) {
    fill_w(W, PITCH0, 0, Wih0f, 128, base_h);
    fill_w(W, PITCH0, 128, Whh0, 1024, base_h);
  } else {
    fill_w(W, PITCH, 0, Wih1, 1024, base_h);
    fill_w(W, PITCH, 1024, Whh1, 1024, base_h);
  }
  __syncthreads();
  const float* bias = isL0 ? b0f : b1f;
  float bb0 = bias[(c >> 3) * 1024 + base_h + (c & 7)];
  float bb1 = bias[(2 + (c >> 3)) * 1024 + base_h + (c & 7)];
  float cst[4] = {0.f, 0.f, 0.f, 0.f};
  int hcol_g = base_h + (c & 7);

  for (int t = 0; t <= 1024; ++t) {
    if (isL0) {
      if (t < 1024) {
        f32x4 a0 = {0.f,0.f,0.f,0.f}, a1 = {0.f,0.f,0.f,0.f};
        const hbf16* h0r = (t & 1) ? h0_0 : h0_1;   // h0(t-1)
        seg_asm(a0, a1, h0r, 1024L, W, PITCH0, 128, w, q, c);  // coherent first
        seg_x(a0, a1, xb + (long)t * 128, 131072L, W, PITCH0, w, q, c);
        hbf16* h0w = (t & 1) ? h0_1 : h0_0;         // h0(t)
        cell(a0, a1, bb0, bb1, cst, h0w, base_h, lane, w);
        if (t == 1023) store_c(cst, c0buf, hcol_g, lane, w);
      }
    } else {
      if (t >= 1) {   // computes h1(t-1)
        f32x4 a0 = {0.f,0.f,0.f,0.f}, a1 = {0.f,0.f,0.f,0.f};
        const hbf16* h0r = (t & 1) ? h0_0 : h0_1;   // h0(t-1)
        seg_asm(a0, a1, h0r, 1024L, W, PITCH, 0, w, q, c);
        const hbf16* h1r = (t & 1) ? h1_1 : h1_0;   // h1(t-2)
        seg_asm(a0, a1, h1r, 1024L, W, PITCH, 1024, w, q, c);
        hbf16* h1w = (t & 1) ? h1_0 : h1_1;         // h1(t-1)
        cell(a0, a1, bb0, bb1, cst, h1w, base_h, lane, w);
        if (t == 1024) store_c(cst, c1buf, hcol_g, lane, w);
      }
    }
    if (t < 1024) gbar(flags, t + 1);
  }
}

// ================= decoder persistent kernel =================
__global__ __launch_bounds__(256, 1) void k_dec(
    const hbf16* __restrict__ Wfold, const hbf16* __restrict__ Whh0d,
    const hbf16* __restrict__ Wih1d, const hbf16* __restrict__ Whh1d,
    const float* __restrict__ b0t, const float* __restrict__ b0p,
    const float* __restrict__ b1d,
    const hbf16* __restrict__ fc1Wf, const float* __restrict__ fc1bf,
    const float* __restrict__ fs2, const float* __restrict__ fadd2,
    const hbf16* __restrict__ fc2Wb, const float* __restrict__ fc2b,
    hbf16* d0_0, hbf16* d0_1, hbf16* d1_0, hbf16* d1_1, hbf16* f1b,
    const float* __restrict__ c0buf, const float* __restrict__ c1buf,
    float* __restrict__ out, int* flags) {
  __shared__ hbf16 W[32 * PITCH];
  __shared__ float bounce[4][64][16];
  int wg = blockIdx.x, tid = threadIdx.x;
  int lane = tid & 63, w = tid >> 6, q = lane >> 4, c = lane & 15;
  bool isP1 = wg < 128;
  int cu = isP1 ? wg : wg - 128;
  int base_h = cu * 8;
  if (isP1) {
    fill_w(W, PITCH, 0, Wfold, 1024, base_h);
    fill_w(W, PITCH, 1024, Whh0d, 1024, base_h);
  } else {
    fill_w(W, PITCH, 0, Wih1d, 1024, base_h);
    fill_w(W, PITCH, 1024, Whh1d, 1024, base_h);
  }
  __syncthreads();
  int gi0 = (c >> 3) * 1024 + base_h + (c & 7);
  int gi1 = (2 + (c >> 3)) * 1024 + base_h + (c & 7);
  float bt0, bt1, bp0, bp1;
  if (isP1) { bt0 = b0t[gi0]; bt1 = b0t[gi1]; bp0 = b0p[gi0]; bp1 = b0p[gi1]; }
  else      { bt0 = b1d[gi0]; bt1 = b1d[gi1]; bp0 = bt0;      bp1 = bt1; }
  int hcol_g = base_h + (c & 7);
  float cst[4] = {0.f, 0.f, 0.f, 0.f};
  {   // cell-state handoff from encoder (cross-kernel: plain loads OK)
    const float* cb = isP1 ? c0buf : c1buf;
    if (c < 8) {
#pragma unroll
      for (int r = 0; r < 4; ++r)
        cst[r] = cb[(long)(w * 16 + q * 4 + r) * 1024 + hcol_g];
    }
  }
  // aux roles: fc1 on wg<64 (subset of p1), pred/fc2 on wg 128..135 (subset of p2)
  bool isP3 = (wg < 64);
  bool isPred = (wg >= 128 && wg < 136);
  bf16x8 fr[8];
#pragma unroll
  for (int i = 0; i < 8; ++i) fr[i] = bf16x8{0,0,0,0,0,0,0,0};
  float e_b[4] = {0,0,0,0}, e_s[4] = {0,0,0,0}, e_a[4] = {0,0,0,0};
  int red_row = tid >> 2, red_c4 = (tid & 3) * 4;
  if (isP3) {
    const hbf16* fp = fc1Wf + (long)(wg * 16 + c) * 1024 + w * 256 + q * 8;
#pragma unroll
    for (int i = 0; i < 8; ++i) fr[i] = *reinterpret_cast<const bf16x8*>(fp + i * 32);
#pragma unroll
    for (int i = 0; i < 4; ++i) {
      int col = wg * 16 + red_c4 + i;
      e_b[i] = fc1bf[col]; e_s[i] = fs2[col]; e_a[i] = fadd2[col];
    }
  } else if (isPred) {
    const hbf16* fp = fc2Wb + (long)((wg - 128) * 16 + c) * 1024 + w * 256 + q * 8;
#pragma unroll
    for (int i = 0; i < 8; ++i) fr[i] = *reinterpret_cast<const bf16x8*>(fp + i * 32);
#pragma unroll
    for (int i = 0; i < 4; ++i) e_b[i] = fc2b[(wg - 128) * 16 + red_c4 + i];
  }

  // Persistent recurrent partials, carried across barriers (8 f32 regs).
  // p1: r0/r1 = d0(t-1) @ Whh0d (computed in I2/I3 of step t-1)
  // p2: r0/r1 = d1(t-1) @ Whh1d (computed in I3 of step t-1)
  f32x4 r0 = {0.f,0.f,0.f,0.f}, r1 = {0.f,0.f,0.f,0.f};

  for (int t = 0; t <= 1024; ++t) {
    // ---- interval 1: p1 gates d0(t) (f1b seg + held recurrent partial);
    //                  pred(t-1) on pred-CUs; p2 t=0 bootstrap.
    if (isP1 && t < 1024) {
      f32x4 a0 = r0, a1 = r1;
      if (t > 0) {
        seg_asm(a0, a1, f1b, 1024L, W, PITCH, 0, w, q, c);
      } else {
        // t=0: y(0)=0 (no f1 input); recurrent operand is enc h0 final (d0_1),
        // no prior interval existed -> compute it inline here.
        seg_asm(a0, a1, d0_1, 1024L, W, PITCH, 1024, w, q, c);
      }
      float B0 = (t > 0) ? bt0 : bp0, B1 = (t > 0) ? bt1 : bp1;
      hbf16* d0w = (t & 1) ? d0_1 : d0_0;           // d0(t)
      cell(a0, a1, B0, B1, cst, d0w, base_h, lane, w);
    }
    if (!isP1 && t == 0) {
      // bootstrap p2's recurrent partial: d1(-1) = enc h1 final (d1_1)
      seg_asm(r0, r1, d1_1, 1024L, W, PITCH, 1024, w, q, c);
    }
    if (isPred && t >= 1) {   // pred(t-1) = f1(t-1)@fc2^T + fc2_b -> out
      f32x4 pa[4] = {{0.f,0.f,0.f,0.f},{0.f,0.f,0.f,0.f},{0.f,0.f,0.f,0.f},{0.f,0.f,0.f,0.f}};
      mm4_asm(pa, f1b + (long)c * 1024 + w * 256 + q * 8, fr);
#pragma unroll
      for (int mt = 0; mt < 4; ++mt)
#pragma unroll
        for (int r = 0; r < 4; ++r) bounce[w][mt * 16 + q * 4 + r][c] = pa[mt][r];
      __syncthreads();
#pragma unroll
      for (int i = 0; i < 4; ++i) {
        int cc = red_c4 + i;
        float s = bounce[0][red_row][cc] + bounce[1][red_row][cc] +
                  bounce[2][red_row][cc] + bounce[3][red_row][cc] + e_b[i];
        out[(long)red_row * 131072 + (long)(t - 1) * 128 + (wg - 128) * 16 + cc] = s;
      }
    }
    if (t == 1024) break;
    gbar(flags, 3 * t + 1);
    // ---- interval 2: p2 gates d1(t) (d0(t) seg + held recurrent partial);
    //                  p3-half of p1 precomputes d0r partial for t+1.
    if (!isP1) {
      f32x4 a0 = r0, a1 = r1;
      const hbf16* d0c = (t & 1) ? d0_1 : d0_0;     // d0(t)
      seg_asm(a0, a1, d0c, 1024L, W, PITCH, 0, w, q, c);
      hbf16* d1w = (t & 1) ? d1_1 : d1_0;           // d1(t)
      cell(a0, a1, bt0, bt1, cst, d1w, base_h, lane, w);
    } else if (isP3 && t < 1023) {
      r0 = f32x4{0.f,0.f,0.f,0.f}; r1 = f32x4{0.f,0.f,0.f,0.f};
      const hbf16* d0n = (t & 1) ? d0_1 : d0_0;     // d0(t), visible post-gbar
      seg_asm(r0, r1, d0n, 1024L, W, PITCH, 1024, w, q, c);
    }
    gbar(flags, 3 * t + 2);
    // ---- interval 3: f1(t) on wg<64; p2 precomputes d1r partial for t+1;
    //                  p1-rest precomputes d0r partial for t+1.
    if (isP3) {
      const hbf16* d1c = (t & 1) ? d1_1 : d1_0;     // d1(t)
      f32x4 pa[4] = {{0.f,0.f,0.f,0.f},{0.f,0.f,0.f,0.f},{0.f,0.f,0.f,0.f},{0.f,0.f,0.f,0.f}};
      mm4_asm(pa, d1c + (long)c * 1024 + w * 256 + q * 8, fr);
#pragma unroll
      for (int mt = 0; mt < 4; ++mt)
#pragma unroll
        for (int r = 0; r < 4; ++r) bounce[w][mt * 16 + q * 4 + r][c] = pa[mt][r];
      __syncthreads();
#pragma unroll
      for (int i = 0; i < 4; ++i) {
        int cc = red_c4 + i;
        float s = bounce[0][red_row][cc] + bounce[1][red_row][cc] +
                  bounce[2][red_row][cc] + bounce[3][red_row][cc];
        float v = fmaxf((s + e_b[i]) * e_s[i] + e_a[i], 0.f);
        bounce[0][red_row][cc] = v;   // stage for packed store
      }
      {
        union { unsigned short s4[4]; unsigned long long u; } pk;
#pragma unroll
        for (int i = 0; i < 4; ++i) pk.s4[i] = bf_bits(bounce[0][red_row][red_c4 + i]);
        st_u64_coh(f1b + (long)red_row * 1024 + wg * 16 + red_c4, pk.u);
      }
    } else if (isP1 && t < 1023) {   // wg 64..127
      r0 = f32x4{0.f,0.f,0.f,0.f}; r1 = f32x4{0.f,0.f,0.f,0.f};
      const hbf16* d0n = (t & 1) ? d0_1 : d0_0;     // d0(t)
      seg_asm(r0, r1, d0n, 1024L, W, PITCH, 1024, w, q, c);
    }
    if (!isP1 && t < 1023) {
      r0 = f32x4{0.f,0.f,0.f,0.f}; r1 = f32x4{0.f,0.f,0.f,0.f};
      const hbf16* d1n = (t & 1) ? d1_1 : d1_0;     // d1(t)
      seg_asm(r0, r1, d1n, 1024L, W, PITCH, 1024, w, q, c);
    }
    gbar(flags, 3 * t + 3);
  }
}

// ================= prep kernels (verified in R2) =================

__global__ void k_cast_bf16(const float* __restrict__ s, hbf16* __restrict__ d, long n) {
  long i = (long)blockIdx.x * blockDim.x + threadIdx.x;
  long stride = (long)gridDim.x * blockDim.x;
  for (; i < n; i += stride) d[i] = __float2bfloat16(s[i]);
}

__global__ void k_prep_b0tot(const float* __restrict__ dec_b0, const float* __restrict__ dWih0,
                             const float* __restrict__ fc2b, float* __restrict__ b0d_tot) {
  int n = blockIdx.x * 256 + threadIdx.x;
  float acc = 0.f;
  for (int cc = 0; cc < 128; ++cc) acc += dWih0[n * 128 + cc] * fc2b[cc];
  b0d_tot[n] = dec_b0[n] + acc;
}

__global__ void k_fold_ih0(const float* __restrict__ g, const float* __restrict__ bb,
                           const float* __restrict__ m, const float* __restrict__ v,
                           const float* __restrict__ Wm, const float* __restrict__ b0,
                           hbf16* __restrict__ Wf, float* __restrict__ biasf) {
  int n = blockIdx.x * 256 + threadIdx.x;
  float acc = 0.f;
  for (int k = 0; k < 128; ++k) {
    float s = g[k] * rsqrtf(v[k] + 1e-5f);
    float tt = bb[k] - m[k] * s;
    float wv = Wm[n * 128 + k];
    Wf[n * 128 + k] = __float2bfloat16(wv * s);
    acc += tt * wv;
  }
  biasf[n] = b0[n] + acc;
}

__global__ void k_fold_fc1(const float* __restrict__ hg, const float* __restrict__ hb,
                           const float* __restrict__ hm, const float* __restrict__ hv,
                           const float* __restrict__ Wm, const float* __restrict__ fb,
                           const float* __restrict__ fg, const float* __restrict__ fbb,
                           const float* __restrict__ fm, const float* __restrict__ fv,
                           hbf16* __restrict__ Wf, float* __restrict__ bfo,
                           float* __restrict__ fs2, float* __restrict__ fadd2) {
  int n = blockIdx.x * 256 + threadIdx.x;
  float acc = 0.f;
  for (int k = 0; k < 1024; ++k) {
    float s = hg[k] * rsqrtf(hv[k] + 1e-5f);
    float tt = hb[k] - hm[k] * s;
    float wv = Wm[(long)n * 1024 + k];
    Wf[(long)n * 1024 + k] = __float2bfloat16(wv * s);
    acc += tt * wv;
  }
  bfo[n] = fb[n] + acc;
  float s2 = fg[n] * rsqrtf(fv[n] + 1e-5f);
  fs2[n] = s2;
  fadd2[n] = fbb[n] - fm[n] * s2;
}

__global__ void k_fold_wf(const float* __restrict__ Wih0d, const float* __restrict__ fc2W,
                          hbf16* __restrict__ Wfold) {
  long gid = (long)blockIdx.x * 256 + threadIdx.x;
  int n = (int)(gid >> 10), jcol = (int)(gid & 1023);
  float acc = 0.f;
  for (int cc = 0; cc < 128; ++cc)
    acc += Wih0d[n * 128 + cc] * fc2W[cc * 1024 + jcol];
  Wfold[gid] = __float2bfloat16(acc);
}

// ================= host =================

extern "C" void kernel_launch(void* const* d_in, const int* in_sizes, int n_in,
                              void* d_out, int out_size, void* d_ws, size_t ws_size,
                              hipStream_t stream) {
  (void)in_sizes; (void)n_in; (void)out_size; (void)ws_size;
  const float* x     = (const float*)d_in[0];
  const float* ibn_g = (const float*)d_in[1];
  const float* ibn_b = (const float*)d_in[2];
  const float* ibn_m = (const float*)d_in[3];
  const float* ibn_v = (const float*)d_in[4];
  const float* eWih0 = (const float*)d_in[5];
  const float* eWhh0 = (const float*)d_in[6];
  const float* e_b0  = (const float*)d_in[7];
  const float* eWih1 = (const float*)d_in[8];
  const float* eWhh1 = (const float*)d_in[9];
  const float* e_b1  = (const float*)d_in[10];
  const float* dWih0 = (const float*)d_in[11];
  const float* dWhh0 = (const float*)d_in[12];
  const float* d_b0  = (const float*)d_in[13];
  const float* dWih1 = (const float*)d_in[14];
  const float* dWhh1 = (const float*)d_in[15];
  const float* d_b1  = (const float*)d_in[16];
  const float* hbn_g = (const float*)d_in[17];
  const float* hbn_b = (const float*)d_in[18];
  const float* hbn_m = (const float*)d_in[19];
  const float* hbn_v = (const float*)d_in[20];
  const float* fc1_W = (const float*)d_in[21];
  const float* fc1_b = (const float*)d_in[22];
  const float* fbn_g = (const float*)d_in[23];
  const float* fbn_b = (const float*)d_in[24];
  const float* fbn_m = (const float*)d_in[25];
  const float* fbn_v = (const float*)d_in[26];
  const float* fc2_W = (const float*)d_in[27];
  const float* fc2_b = (const float*)d_in[28];
  float* out = (float*)d_out;

  char* p = (char*)d_ws;
  auto alloc = [&](size_t bytes) -> void* {
    void* r = (void*)p;
    p += (bytes + 255) & ~(size_t)255;
    return r;
  };
  hbf16* xb     = (hbf16*)alloc(64L * 1024 * 128 * 2);
  hbf16* Wih0f  = (hbf16*)alloc(4096L * 128 * 2);
  hbf16* Whh0e  = (hbf16*)alloc(4096L * 1024 * 2);
  hbf16* Wih1e  = (hbf16*)alloc(4096L * 1024 * 2);
  hbf16* Whh1e  = (hbf16*)alloc(4096L * 1024 * 2);
  hbf16* Wfold  = (hbf16*)alloc(4096L * 1024 * 2);
  hbf16* Whh0d  = (hbf16*)alloc(4096L * 1024 * 2);
  hbf16* Wih1d  = (hbf16*)alloc(4096L * 1024 * 2);
  hbf16* Whh1d  = (hbf16*)alloc(4096L * 1024 * 2);
  hbf16* fc1Wf  = (hbf16*)alloc(1024L * 1024 * 2);
  hbf16* fc2Wb  = (hbf16*)alloc(128L * 1024 * 2);
  float* bias0f = (float*)alloc(4096 * 4);
  float* b0dtot = (float*)alloc(4096 * 4);
  float* fc1bf  = (float*)alloc(1024 * 4);
  float* fs2    = (float*)alloc(1024 * 4);
  float* fadd2  = (float*)alloc(1024 * 4);
  char* st = p;  // zero-init region
  hbf16* h0_0 = (hbf16*)alloc(64L * 1024 * 2);
  hbf16* h0_1 = (hbf16*)alloc(64L * 1024 * 2);
  hbf16* h1_0 = (hbf16*)alloc(64L * 1024 * 2);
  hbf16* h1_1 = (hbf16*)alloc(64L * 1024 * 2);
  float* c0b  = (float*)alloc(64L * 1024 * 4);
  float* c1b  = (float*)alloc(64L * 1024 * 4);
  hbf16* f1b  = (hbf16*)alloc(64L * 1024 * 2);
  int*   flagsE = (int*)alloc(256 * 4);
  int*   flagsD = (int*)alloc(256 * 4);
  size_t stbytes = (size_t)(p - st);

  hipMemsetAsync(st, 0, stbytes, stream);

  k_cast_bf16<<<4096, 256, 0, stream>>>(x, xb, 64L * 1024 * 128);
  k_cast_bf16<<<2048, 256, 0, stream>>>(eWhh0, Whh0e, 4096L * 1024);
  k_cast_bf16<<<2048, 256, 0, stream>>>(eWih1, Wih1e, 4096L * 1024);
  k_cast_bf16<<<2048, 256, 0, stream>>>(eWhh1, Whh1e, 4096L * 1024);
  k_cast_bf16<<<2048, 256, 0, stream>>>(dWhh0, Whh0d, 4096L * 1024);
  k_cast_bf16<<<2048, 256, 0, stream>>>(dWih1, Wih1d, 4096L * 1024);
  k_cast_bf16<<<2048, 256, 0, stream>>>(dWhh1, Whh1d, 4096L * 1024);
  k_cast_bf16<<<512, 256, 0, stream>>>(fc2_W, fc2Wb, 128L * 1024);
  k_prep_b0tot<<<16, 256, 0, stream>>>(d_b0, dWih0, fc2_b, b0dtot);
  k_fold_ih0<<<16, 256, 0, stream>>>(ibn_g, ibn_b, ibn_m, ibn_v, eWih0, e_b0, Wih0f, bias0f);
  k_fold_fc1<<<4, 256, 0, stream>>>(hbn_g, hbn_b, hbn_m, hbn_v, fc1_W, fc1_b,
                                    fbn_g, fbn_b, fbn_m, fbn_v, fc1Wf, fc1bf, fs2, fadd2);
  k_fold_wf<<<16384, 256, 0, stream>>>(dWih0, fc2_W, Wfold);

  k_enc<<<256, 256, 0, stream>>>(xb, Wih0f, Whh0e, Wih1e, Whh1e, bias0f, e_b1,
                                 h0_0, h0_1, h1_0, h1_1, c0b, c1b, flagsE);

  k_dec<<<256, 256, 0, stream>>>(Wfold, Whh0d, Wih1d, Whh1d, b0dtot, d_b0, d_b1,
                                 fc1Wf, fc1bf, fs2, fadd2, fc2Wb, fc2_b,
                                 h0_0, h0_1, h1_0, h1_1, f1b, c0b, c1b, out, flagsD);
}